// Round 4
// baseline (380.826 us; speedup 1.0000x reference)
//
#include <hip/hip_runtime.h>
#include <stdint.h>

#define BB 4
#define CCH 64
#define NN 9216      // 96*96
#define NTILES 144   // NN/64  (qkv/out kernels: 64-wide n tiles)
#define FTILES 72    // NN/128 (flash: 128 Q-rows per block)
#define NCHUNK 4     // split-K chunks
#define CHUNKK 2304  // NN/NCHUNK keys per chunk

typedef unsigned short u16;
typedef __attribute__((ext_vector_type(8))) short bhalf8;   // 8 bf16 lanes of an MFMA operand
typedef __attribute__((ext_vector_type(4))) float f32x4;
typedef __attribute__((ext_vector_type(4))) u16 u16x4;
typedef __attribute__((ext_vector_type(8))) u16 u16x8;
typedef __attribute__((ext_vector_type(2))) unsigned int u32x2;

#define MFMA16(a, b, c) __builtin_amdgcn_mfma_f32_16x16x32_bf16((a), (b), (c), 0, 0, 0)

static __device__ __forceinline__ u16 f2bf(float f) {
  union { float f; unsigned u; } v; v.f = f;
  return (u16)((v.u + 0x7fffu + ((v.u >> 16) & 1u)) >> 16);  // RNE
}
static __device__ __forceinline__ float bf2f(u16 h) {
  union { unsigned u; float f; } v; v.u = ((unsigned)h) << 16; return v.f;
}
// pack two f32 -> (bf16(hi)<<16)|bf16(lo), round-half-up, 3 VALU ops total
static __device__ __forceinline__ unsigned pk2(float lo, float hi) {
  unsigned a = __float_as_uint(hi) + 0x8000u;
  unsigned b = __float_as_uint(lo) + 0x8000u;
  return __builtin_amdgcn_perm(a, b, 0x07060302u);  // bytes {a3,a2,b3,b2}
}
// async global->LDS, 16B per lane; lds dest = wave-uniform base + lane*16
static __device__ __forceinline__ void glds16(const void* g, void* l) {
  __builtin_amdgcn_global_load_lds(
      (const __attribute__((address_space(1))) unsigned int*)g,
      (__attribute__((address_space(3))) unsigned int*)l, 16, 0, 0);
}

// ---------------------------------------------------------------------------
// prep: blocks [0,256): per-(b,c) mean/rstd over 9216 spatial elems.
//       blocks [256,320): convert wq,wk,wv,wo (4*4096 f32) to bf16.
// ---------------------------------------------------------------------------
extern "C" __global__ __launch_bounds__(256) void prep_kernel(
    const float* __restrict__ x,
    const float* __restrict__ wq, const float* __restrict__ wk,
    const float* __restrict__ wv, const float* __restrict__ wo,
    float* __restrict__ mean, float* __restrict__ rstd, u16* __restrict__ wbf) {
  if (blockIdx.x >= 256) {
    int i = (blockIdx.x - 256) * 256 + threadIdx.x;  // 0..16383
    const float* src = (i < 4096) ? wq : (i < 8192) ? wk : (i < 12288) ? wv : wo;
    wbf[i] = f2bf(src[i & 4095]);
    return;
  }
  int idx = blockIdx.x;
  const float* p = x + (size_t)idx * NN;
  float s = 0.f, ss = 0.f;
  for (int i = threadIdx.x; i < NN; i += 256) { float v = p[i]; s += v; ss += v * v; }
#pragma unroll
  for (int o = 32; o > 0; o >>= 1) { s += __shfl_xor(s, o, 64); ss += __shfl_xor(ss, o, 64); }
  __shared__ float ls[4], lss[4];
  int w = threadIdx.x >> 6;
  if ((threadIdx.x & 63) == 0) { ls[w] = s; lss[w] = ss; }
  __syncthreads();
  if (threadIdx.x == 0) {
    s = ls[0] + ls[1] + ls[2] + ls[3];
    ss = lss[0] + lss[1] + lss[2] + lss[3];
    float m = s * (1.f / NN);
    float var = ss * (1.f / NN) - m * m;
    mean[idx] = m;
    rstd[idx] = rsqrtf(var + 1e-5f);
  }
}

// ---------------------------------------------------------------------------
// qkv: fused instance-norm + 1x1 convs via MFMA.
// Qt,Kt = [B][N][64] bf16 (Q pre-scaled by 0.125*log2e), Vt = [B][64][N] bf16.
// ---------------------------------------------------------------------------
extern "C" __global__ __launch_bounds__(256, 4) void qkv_kernel(
    const float* __restrict__ x,
    const float* __restrict__ mean, const float* __restrict__ rstd,
    const u16* __restrict__ wqb, const u16* __restrict__ wkb, const u16* __restrict__ wvb,
    const float* __restrict__ bq, const float* __restrict__ bk,
    u16* __restrict__ Qt, u16* __restrict__ Kt, u16* __restrict__ Vt) {
  __shared__ u16 hbuf[64 * 72];  // [n_local][c], padded rows
  int b = blockIdx.x / NTILES, tile = blockIdx.x % NTILES;
  int n0 = tile * 64;
  int t = threadIdx.x;
  int w = t >> 6, lane = t & 63, q = lane >> 4, ln = lane & 15;
  const float QSCALE = 0.125f * 1.44269504088896340736f;  // C^-0.5 * log2(e)
#pragma unroll
  for (int rep = 0; rep < 16; rep++) {
    int c = rep * 4 + w;
    float v = x[(size_t)(b * 64 + c) * NN + n0 + lane];
    float h = (v - mean[b * 64 + c]) * rstd[b * 64 + c];
    hbuf[lane * 72 + c] = f2bf(h);
  }
  __syncthreads();
  int hrow = (16 * w + ln) * 72;
  bhalf8 hb0 = *(const bhalf8*)&hbuf[hrow + q * 8];
  bhalf8 hb1 = *(const bhalf8*)&hbuf[hrow + 32 + q * 8];
  size_t nrow = (size_t)(b * NN + n0 + 16 * w + ln) * 64;
  // ---- Q (transposed orientation: reg quad = 4 consecutive channels) ----
#pragma unroll
  for (int ct = 0; ct < 4; ct++) {
    int wrow = (16 * ct + ln) * 64;
    bhalf8 a0 = *(const bhalf8*)&wqb[wrow + q * 8];
    bhalf8 a1 = *(const bhalf8*)&wqb[wrow + 32 + q * 8];
    f32x4 d = {0.f, 0.f, 0.f, 0.f};
    d = MFMA16(a0, hb0, d);
    d = MFMA16(a1, hb1, d);
    f32x4 b4 = *(const f32x4*)&bq[16 * ct + 4 * q];
    u16x4 pk;
#pragma unroll
    for (int r = 0; r < 4; r++) pk[r] = f2bf((d[r] + b4[r]) * QSCALE);
    *(u16x4*)&Qt[nrow + 16 * ct + 4 * q] = pk;
  }
  // ---- K ----
#pragma unroll
  for (int ct = 0; ct < 4; ct++) {
    int wrow = (16 * ct + ln) * 64;
    bhalf8 a0 = *(const bhalf8*)&wkb[wrow + q * 8];
    bhalf8 a1 = *(const bhalf8*)&wkb[wrow + 32 + q * 8];
    f32x4 d = {0.f, 0.f, 0.f, 0.f};
    d = MFMA16(a0, hb0, d);
    d = MFMA16(a1, hb1, d);
    f32x4 b4 = *(const f32x4*)&bk[16 * ct + 4 * q];
    u16x4 pk;
#pragma unroll
    for (int r = 0; r < 4; r++) pk[r] = f2bf(d[r] + b4[r]);
    *(u16x4*)&Kt[nrow + 16 * ct + 4 * q] = pk;
  }
  // ---- V (normal orientation; bv folded into epilogue) ----
#pragma unroll
  for (int ct = 0; ct < 4; ct++) {
    int wrow = (16 * ct + ln) * 64;
    bhalf8 b0 = *(const bhalf8*)&wvb[wrow + q * 8];
    bhalf8 b1 = *(const bhalf8*)&wvb[wrow + 32 + q * 8];
    f32x4 d = {0.f, 0.f, 0.f, 0.f};
    d = MFMA16(hb0, b0, d);
    d = MFMA16(hb1, b1, d);
    u16x4 pk;
#pragma unroll
    for (int r = 0; r < 4; r++) pk[r] = f2bf(d[r]);
    *(u16x4*)&Vt[(size_t)(b * 64 + 16 * ct + ln) * NN + n0 + 16 * w + 4 * q] = pk;
  }
}

// ---------------------------------------------------------------------------
// flash: split-K attention, MAX-FREE softmax (scores bounded by instance
// norm: |s*log2e| << 88, so exp2 of raw scores cannot overflow fp32).
// P = exp2(s_raw) unnormalized; l accumulated via ones-A MFMA; m stored as 0.
// Block = 4 waves x 32 Q-rows = 128 rows; one of 4 key-chunks (2304 keys).
// LDS exactly 32KB -> 5 blocks/CU -> all 1152 blocks co-resident.
// ---------------------------------------------------------------------------
extern "C" __global__ __launch_bounds__(256, 5) void flash_kernel(
    const u16* __restrict__ Qt, const u16* __restrict__ Kt, const u16* __restrict__ Vt,
    u16* __restrict__ Opart, float* __restrict__ Ml) {
  __shared__ u16 kbuf[64 * 64];        // [m_local][c], 16B units swizzled by (row&7)
  __shared__ u16 vbuf[64 * 64];        // [c][m_local], 16B units swizzled by (row&7)
  __shared__ u16 pbuf[4 * 32 * 64];    // per-wave [n_local(32)][m], swizzled
  int blk = blockIdx.x;
  int b = blk / (FTILES * NCHUNK);
  int rem = blk % (FTILES * NCHUNK);
  int tile = rem >> 2, chunk = rem & 3;
  int m_start = chunk * CHUNKK;
  int t = threadIdx.x;
  int w = t >> 6, lane = t & 63, q = lane >> 4, ln = lane & 15;
  int n0w = tile * 128 + 32 * w;
  // Q fragments for 32 rows: set a = rows [n0w, n0w+16), set b = +16
  const u16* qp = Qt + (size_t)(b * NN + n0w + ln) * 64 + q * 8;
  bhalf8 qa0 = *(const bhalf8*)qp;
  bhalf8 qa1 = *(const bhalf8*)(qp + 32);
  bhalf8 qb0 = *(const bhalf8*)(qp + 16 * 64);
  bhalf8 qb1 = *(const bhalf8*)(qp + 16 * 64 + 32);
  const short ONE = 0x3F80;            // bf16 1.0
  const bhalf8 ones = {ONE, ONE, ONE, ONE, ONE, ONE, ONE, ONE};
  f32x4 oa[4], ob[4];
  f32x4 lacc_a = {0.f, 0.f, 0.f, 0.f}, lacc_b = {0.f, 0.f, 0.f, 0.f};
#pragma unroll
  for (int i = 0; i < 4; i++) { oa[i] = (f32x4){0.f,0.f,0.f,0.f}; ob[i] = (f32x4){0.f,0.f,0.f,0.f}; }
  u16* pb = pbuf + w * 2048;           // 32 rows * 64 per wave
  // staging: wave w fills LDS rows [16w,16w+16); lane covers (row 16w+(lane>>3), unit lane&7)
  int row_s = 16 * w + (lane >> 3);
  int usw = (lane & 7) ^ (row_s & 7);  // swizzled global 16B-chunk index
  const u16* kgp = Kt + ((size_t)b * NN + m_start + row_s) * 64 + usw * 8;
  const u16* vgp = Vt + (size_t)(b * 64 + row_s) * NN + m_start + usw * 8;
  u16* klds = &kbuf[w * 1024];
  u16* vlds = &vbuf[w * 1024];
  int sbase = (q ^ (ln & 7)) * 8;      // swizzled chunk offset for fragment reads

  for (int m0 = 0; m0 < CHUNKK; m0 += 64) {
    __syncthreads();                   // all waves done reading previous tile
    glds16(kgp, klds);
    glds16(kgp + 512, klds + 512);     // rows +8 (same swizzle: (r+8)&7 == r&7)
    glds16(vgp, vlds);
    glds16(vgp + (size_t)8 * NN, vlds + 512);
    kgp += 64 * 64;
    vgp += 64;
    __syncthreads();                   // staged data visible

    // S^T: lane holds m = 16*mt + 4*q + r ; n = ln (set a) / ln+16 (set b)
    f32x4 sa[4], sb[4];
#pragma unroll
    for (int mt = 0; mt < 4; mt++) {
      int krow = (16 * mt + ln) * 64;
      bhalf8 ka0 = *(const bhalf8*)&kbuf[krow + sbase];
      bhalf8 ka1 = *(const bhalf8*)&kbuf[krow + (sbase ^ 32)];
      f32x4 acc = {0.f, 0.f, 0.f, 0.f};
      acc = MFMA16(ka0, qa0, acc);
      acc = MFMA16(ka1, qa1, acc);
      sa[mt] = acc;
      f32x4 acc2 = {0.f, 0.f, 0.f, 0.f};
      acc2 = MFMA16(ka0, qb0, acc2);
      acc2 = MFMA16(ka1, qb1, acc2);
      sb[mt] = acc2;
    }
    // max-free: P = exp2(raw score), pack to bf16, store to per-wave pbuf
#pragma unroll
    for (int mt = 0; mt < 4; mt++) {
      f32x4 pa, pbv;
#pragma unroll
      for (int r = 0; r < 4; r++) {
        pa[r] = __builtin_amdgcn_exp2f(sa[mt][r]);
        pbv[r] = __builtin_amdgcn_exp2f(sb[mt][r]);
      }
      int pu = (((2 * mt + (q >> 1)) ^ (ln & 7)) << 3) + ((q & 1) << 2);  // swizzled unit + 8B sub
      u32x2 pk;
      pk[0] = pk2(pa[0], pa[1]);
      pk[1] = pk2(pa[2], pa[3]);
      *(u32x2*)&pb[ln * 64 + pu] = pk;
      pk[0] = pk2(pbv[0], pbv[1]);
      pk[1] = pk2(pbv[2], pbv[3]);
      *(u32x2*)&pb[(16 + ln) * 64 + pu] = pk;
    }
    // PV: O^T += V^T * P^T ; l via ones-A MFMA (all D rows = column sums)
#pragma unroll
    for (int s2 = 0; s2 < 2; s2++) {
      bhalf8 pfa = *(const bhalf8*)&pb[ln * 64 + (sbase ^ (32 * s2))];
      bhalf8 pfb = *(const bhalf8*)&pb[(16 + ln) * 64 + (sbase ^ (32 * s2))];
      lacc_a = MFMA16(ones, pfa, lacc_a);
      lacc_b = MFMA16(ones, pfb, lacc_b);
#pragma unroll
      for (int ct = 0; ct < 4; ct++) {
        int vrow = (16 * ct + ln) * 64;
        bhalf8 va = *(const bhalf8*)&vbuf[vrow + (sbase ^ (32 * s2))];
        oa[ct] = MFMA16(va, pfa, oa[ct]);
        ob[ct] = MFMA16(va, pfb, ob[ct]);
      }
    }
  }
  // emit partial (unnormalized O in bf16, m=0 / l per row)
  size_t pbase = (size_t)blk * (128 * 64);
  int ra = 32 * w + ln, rb = ra + 16;
#pragma unroll
  for (int ct = 0; ct < 4; ct++) {
    u32x2 pka, pkb;
    pka[0] = pk2(oa[ct][0], oa[ct][1]); pka[1] = pk2(oa[ct][2], oa[ct][3]);
    pkb[0] = pk2(ob[ct][0], ob[ct][1]); pkb[1] = pk2(ob[ct][2], ob[ct][3]);
    *(u32x2*)&Opart[pbase + (size_t)ra * 64 + 16 * ct + 4 * q] = pka;
    *(u32x2*)&Opart[pbase + (size_t)rb * 64 + 16 * ct + 4 * q] = pkb;
  }
  if (q == 0) {
    float* mlb = Ml + (size_t)blk * 256;
    mlb[ra * 2] = 0.f; mlb[ra * 2 + 1] = lacc_a[0];
    mlb[rb * 2] = 0.f; mlb[rb * 2 + 1] = lacc_b[0];
  }
}

// ---------------------------------------------------------------------------
// out (fused merge + projection + residual):
// merge 4 split-K partials inline -> o rows (bf16 A-fragments), then
// out = x + Wo*o + bo via MFMA, float4 stores.
// ---------------------------------------------------------------------------
extern "C" __global__ __launch_bounds__(256, 4) void out_kernel(
    const float* __restrict__ x, const u16* __restrict__ wob, const float* __restrict__ bo,
    const u16* __restrict__ Opart, const float* __restrict__ Ml, const float* __restrict__ bv,
    float* __restrict__ out) {
  int b = blockIdx.x / NTILES, tile = blockIdx.x % NTILES;
  int t = threadIdx.x;
  int w = t >> 6, lane = t & 63, q = lane >> 4, ln = lane & 15;
  int n0w = tile * 64 + 16 * w;
  // flash partial indexing for this lane's A-row (n = n0w + ln)
  int ptile = tile >> 1;
  int prow = (tile & 1) * 64 + 16 * w + ln;
  int p0 = (b * FTILES + ptile) * NCHUNK;
  float mc[4], lc[4];
#pragma unroll
  for (int ch = 0; ch < 4; ch++) {
    const float* mlb = Ml + (size_t)(p0 + ch) * 256 + prow * 2;
    mc[ch] = mlb[0]; lc[ch] = mlb[1];
  }
  float mstar = fmaxf(fmaxf(mc[0], mc[1]), fmaxf(mc[2], mc[3]));
  float wch[4], L = 0.f;
#pragma unroll
  for (int ch = 0; ch < 4; ch++) { wch[ch] = __builtin_amdgcn_exp2f(mc[ch] - mstar); L += wch[ch] * lc[ch]; }
  float rl = 1.0f / L;
  // merged o for channels {8q..8q+7} (a0) and {32+8q..} (a1)
  float acc0[8], acc1[8];
#pragma unroll
  for (int j = 0; j < 8; j++) { acc0[j] = 0.f; acc1[j] = 0.f; }
#pragma unroll
  for (int ch = 0; ch < 4; ch++) {
    const u16* op = Opart + ((size_t)(p0 + ch) * 128 + prow) * 64;
    u16x8 d0 = *(const u16x8*)(op + 8 * q);
    u16x8 d1 = *(const u16x8*)(op + 32 + 8 * q);
    float wc = wch[ch];
#pragma unroll
    for (int j = 0; j < 8; j++) { acc0[j] += wc * bf2f(d0[j]); acc1[j] += wc * bf2f(d1[j]); }
  }
  union { u16x8 us; bhalf8 bh; } A0, A1;
#pragma unroll
  for (int j = 0; j < 8; j++) {
    A0.us[j] = f2bf(acc0[j] * rl + bv[8 * q + j]);
    A1.us[j] = f2bf(acc1[j] * rl + bv[32 + 8 * q + j]);
  }
  bhalf8 a0 = A0.bh, a1 = A1.bh;
#pragma unroll
  for (int ct = 0; ct < 4; ct++) {
    int wrow = (16 * ct + ln) * 64;
    bhalf8 b0 = *(const bhalf8*)&wob[wrow + q * 8];
    bhalf8 b1 = *(const bhalf8*)&wob[wrow + 32 + q * 8];
    f32x4 d = {0.f, 0.f, 0.f, 0.f};
    d = MFMA16(a0, b0, d);
    d = MFMA16(a1, b1, d);
    int co = 16 * ct + ln;
    size_t base = (size_t)(b * 64 + co) * NN + n0w + 4 * q;
    f32x4 xv = *(const f32x4*)&x[base];
    float bc = bo[co];
    f32x4 ov;
#pragma unroll
    for (int r = 0; r < 4; r++) ov[r] = xv[r] + bc + d[r];
    *(f32x4*)&out[base] = ov;
  }
}

extern "C" void kernel_launch(void* const* d_in, const int* in_sizes, int n_in,
                              void* d_out, int out_size, void* d_ws, size_t ws_size,
                              hipStream_t stream) {
  (void)in_sizes; (void)n_in; (void)out_size; (void)ws_size;
  const float* x  = (const float*)d_in[0];
  const float* wq = (const float*)d_in[1];
  const float* bq = (const float*)d_in[2];
  const float* wk = (const float*)d_in[3];
  const float* bk = (const float*)d_in[4];
  const float* wv = (const float*)d_in[5];
  const float* bv = (const float*)d_in[6];
  const float* wo = (const float*)d_in[7];
  const float* bo = (const float*)d_in[8];
  float* out = (float*)d_out;
  char* ws = (char*)d_ws;
  // workspace layout (16B aligned), ~34.5 MB total
  float* mean = (float*)ws;                   // 256 f32
  float* rstd = (float*)(ws + 1024);          // 256 f32
  u16* wbf = (u16*)(ws + 2048);               // 16384 bf16
  u16* Qt = (u16*)(ws + 36864);               // [B][N][64] bf16  4.72MB
  u16* Kt = Qt + (size_t)BB * NN * 64;
  u16* Vt = Kt + (size_t)BB * NN * 64;
  u16* Opart = Vt + (size_t)BB * NN * 64;     // 1152 * 128*64 bf16 = 18.9MB
  float* Ml = (float*)(Opart + (size_t)BB * FTILES * NCHUNK * 128 * 64);  // 1152*256 f32 = 1.18MB
  const u16* wqb = wbf;
  const u16* wkb = wbf + 4096;
  const u16* wvb = wbf + 8192;
  const u16* wob = wbf + 12288;

  prep_kernel<<<320, 256, 0, stream>>>(x, wq, wk, wv, wo, mean, rstd, wbf);
  qkv_kernel<<<BB * NTILES, 256, 0, stream>>>(x, mean, rstd, wqb, wkb, wvb, bq, bk, Qt, Kt, Vt);
  flash_kernel<<<BB * FTILES * NCHUNK, 256, 0, stream>>>(Qt, Kt, Vt, Opart, Ml);
  out_kernel<<<BB * NTILES, 256, 0, stream>>>(x, wob, bo, Opart, Ml, bv, out);
}

// Round 5
// 220.741 us; speedup vs baseline: 1.7252x; 1.7252x over previous
//
#include <hip/hip_runtime.h>
#include <stdint.h>

#define BB 4
#define CCH 64
#define NN 9216      // 96*96
#define NTILES 144   // NN/64  (qkv/out kernels: 64-wide n tiles)
#define FTILES 72    // NN/128 (flash: 128 Q-rows per block)
#define NCHUNK 3     // split-K chunks (grid 864 <= 1024 resident capacity)
#define CHUNKK 3072  // NN/NCHUNK keys per chunk

typedef unsigned short u16;
typedef __attribute__((ext_vector_type(8))) short bhalf8;   // 8 bf16 lanes of an MFMA operand
typedef __attribute__((ext_vector_type(4))) float f32x4;
typedef __attribute__((ext_vector_type(4))) u16 u16x4;
typedef __attribute__((ext_vector_type(8))) u16 u16x8;
typedef __attribute__((ext_vector_type(2))) unsigned int u32x2;

#define MFMA16(a, b, c) __builtin_amdgcn_mfma_f32_16x16x32_bf16((a), (b), (c), 0, 0, 0)

static __device__ __forceinline__ u16 f2bf(float f) {
  union { float f; unsigned u; } v; v.f = f;
  return (u16)((v.u + 0x7fffu + ((v.u >> 16) & 1u)) >> 16);  // RNE
}
static __device__ __forceinline__ float bf2f(u16 h) {
  union { unsigned u; float f; } v; v.u = ((unsigned)h) << 16; return v.f;
}
// pack two f32 -> (bf16(hi)<<16)|bf16(lo), round-half-up, 3 VALU ops total
static __device__ __forceinline__ unsigned pk2(float lo, float hi) {
  unsigned a = __float_as_uint(hi) + 0x8000u;
  unsigned b = __float_as_uint(lo) + 0x8000u;
  return __builtin_amdgcn_perm(a, b, 0x07060302u);  // bytes {a3,a2,b3,b2}
}
// async global->LDS, 16B per lane; lds dest = wave-uniform base + lane*16
static __device__ __forceinline__ void glds16(const void* g, void* l) {
  __builtin_amdgcn_global_load_lds(
      (const __attribute__((address_space(1))) unsigned int*)g,
      (__attribute__((address_space(3))) unsigned int*)l, 16, 0, 0);
}

// ---------------------------------------------------------------------------
// prep: blocks [0,256): per-(b,c) mean/rstd over 9216 spatial elems.
//       blocks [256,320): convert wq,wk,wv,wo (4*4096 f32) to bf16.
// ---------------------------------------------------------------------------
extern "C" __global__ __launch_bounds__(256) void prep_kernel(
    const float* __restrict__ x,
    const float* __restrict__ wq, const float* __restrict__ wk,
    const float* __restrict__ wv, const float* __restrict__ wo,
    float* __restrict__ mean, float* __restrict__ rstd, u16* __restrict__ wbf) {
  if (blockIdx.x >= 256) {
    int i = (blockIdx.x - 256) * 256 + threadIdx.x;  // 0..16383
    const float* src = (i < 4096) ? wq : (i < 8192) ? wk : (i < 12288) ? wv : wo;
    wbf[i] = f2bf(src[i & 4095]);
    return;
  }
  int idx = blockIdx.x;
  const float* p = x + (size_t)idx * NN;
  float s = 0.f, ss = 0.f;
  for (int i = threadIdx.x; i < NN; i += 256) { float v = p[i]; s += v; ss += v * v; }
#pragma unroll
  for (int o = 32; o > 0; o >>= 1) { s += __shfl_xor(s, o, 64); ss += __shfl_xor(ss, o, 64); }
  __shared__ float ls[4], lss[4];
  int w = threadIdx.x >> 6;
  if ((threadIdx.x & 63) == 0) { ls[w] = s; lss[w] = ss; }
  __syncthreads();
  if (threadIdx.x == 0) {
    s = ls[0] + ls[1] + ls[2] + ls[3];
    ss = lss[0] + lss[1] + lss[2] + lss[3];
    float m = s * (1.f / NN);
    float var = ss * (1.f / NN) - m * m;
    mean[idx] = m;
    rstd[idx] = rsqrtf(var + 1e-5f);
  }
}

// ---------------------------------------------------------------------------
// qkv: fused instance-norm + 1x1 convs via MFMA.
// Qt,Kt = [B][N][64] bf16 (Q pre-scaled by 0.125*log2e), Vt = [B][64][N] bf16.
// ---------------------------------------------------------------------------
extern "C" __global__ __launch_bounds__(256, 4) void qkv_kernel(
    const float* __restrict__ x,
    const float* __restrict__ mean, const float* __restrict__ rstd,
    const u16* __restrict__ wqb, const u16* __restrict__ wkb, const u16* __restrict__ wvb,
    const float* __restrict__ bq, const float* __restrict__ bk,
    u16* __restrict__ Qt, u16* __restrict__ Kt, u16* __restrict__ Vt) {
  __shared__ u16 hbuf[64 * 72];  // [n_local][c], padded rows
  int b = blockIdx.x / NTILES, tile = blockIdx.x % NTILES;
  int n0 = tile * 64;
  int t = threadIdx.x;
  int w = t >> 6, lane = t & 63, q = lane >> 4, ln = lane & 15;
  const float QSCALE = 0.125f * 1.44269504088896340736f;  // C^-0.5 * log2(e)
#pragma unroll
  for (int rep = 0; rep < 16; rep++) {
    int c = rep * 4 + w;
    float v = x[(size_t)(b * 64 + c) * NN + n0 + lane];
    float h = (v - mean[b * 64 + c]) * rstd[b * 64 + c];
    hbuf[lane * 72 + c] = f2bf(h);
  }
  __syncthreads();
  int hrow = (16 * w + ln) * 72;
  bhalf8 hb0 = *(const bhalf8*)&hbuf[hrow + q * 8];
  bhalf8 hb1 = *(const bhalf8*)&hbuf[hrow + 32 + q * 8];
  size_t nrow = (size_t)(b * NN + n0 + 16 * w + ln) * 64;
  // ---- Q (transposed orientation: reg quad = 4 consecutive channels) ----
#pragma unroll
  for (int ct = 0; ct < 4; ct++) {
    int wrow = (16 * ct + ln) * 64;
    bhalf8 a0 = *(const bhalf8*)&wqb[wrow + q * 8];
    bhalf8 a1 = *(const bhalf8*)&wqb[wrow + 32 + q * 8];
    f32x4 d = {0.f, 0.f, 0.f, 0.f};
    d = MFMA16(a0, hb0, d);
    d = MFMA16(a1, hb1, d);
    f32x4 b4 = *(const f32x4*)&bq[16 * ct + 4 * q];
    u16x4 pk;
#pragma unroll
    for (int r = 0; r < 4; r++) pk[r] = f2bf((d[r] + b4[r]) * QSCALE);
    *(u16x4*)&Qt[nrow + 16 * ct + 4 * q] = pk;
  }
  // ---- K ----
#pragma unroll
  for (int ct = 0; ct < 4; ct++) {
    int wrow = (16 * ct + ln) * 64;
    bhalf8 a0 = *(const bhalf8*)&wkb[wrow + q * 8];
    bhalf8 a1 = *(const bhalf8*)&wkb[wrow + 32 + q * 8];
    f32x4 d = {0.f, 0.f, 0.f, 0.f};
    d = MFMA16(a0, hb0, d);
    d = MFMA16(a1, hb1, d);
    f32x4 b4 = *(const f32x4*)&bk[16 * ct + 4 * q];
    u16x4 pk;
#pragma unroll
    for (int r = 0; r < 4; r++) pk[r] = f2bf(d[r] + b4[r]);
    *(u16x4*)&Kt[nrow + 16 * ct + 4 * q] = pk;
  }
  // ---- V (normal orientation; bv folded into epilogue) ----
#pragma unroll
  for (int ct = 0; ct < 4; ct++) {
    int wrow = (16 * ct + ln) * 64;
    bhalf8 b0 = *(const bhalf8*)&wvb[wrow + q * 8];
    bhalf8 b1 = *(const bhalf8*)&wvb[wrow + 32 + q * 8];
    f32x4 d = {0.f, 0.f, 0.f, 0.f};
    d = MFMA16(hb0, b0, d);
    d = MFMA16(hb1, b1, d);
    u16x4 pk;
#pragma unroll
    for (int r = 0; r < 4; r++) pk[r] = f2bf(d[r]);
    *(u16x4*)&Vt[(size_t)(b * 64 + 16 * ct + ln) * NN + n0 + 16 * w + 4 * q] = pk;
  }
}

// ---------------------------------------------------------------------------
// flash: split-K attention, MAX-FREE softmax (instance-normed inputs bound
// |score*log2e| far below the fp32 exp2 overflow point; verified R4).
// P = exp2(s_raw) unnormalized; l via ones-A MFMA; no running max.
// Block = 4 waves x 32 Q-rows = 128 rows; one of 3 key-chunks (3072 keys).
// launch_bounds(256,4): 128-VGPR budget, no spills (R4's (256,5) spilled).
// Grid 864 <= 1024 resident capacity -> single scheduling round.
// ---------------------------------------------------------------------------
extern "C" __global__ __launch_bounds__(256, 4) void flash_kernel(
    const u16* __restrict__ Qt, const u16* __restrict__ Kt, const u16* __restrict__ Vt,
    u16* __restrict__ Opart, float* __restrict__ Lsum) {
  __shared__ u16 kbuf[64 * 64];        // [m_local][c], 16B units swizzled by (row&7)
  __shared__ u16 vbuf[64 * 64];        // [c][m_local], 16B units swizzled by (row&7)
  __shared__ u16 pbuf[4 * 32 * 64];    // per-wave [n_local(32)][m], swizzled
  int blk = blockIdx.x;
  int b = blk / (FTILES * NCHUNK);
  int rem = blk % (FTILES * NCHUNK);
  int tile = rem / NCHUNK, chunk = rem % NCHUNK;
  int m_start = chunk * CHUNKK;
  int t = threadIdx.x;
  int w = t >> 6, lane = t & 63, q = lane >> 4, ln = lane & 15;
  int n0w = tile * 128 + 32 * w;
  // Q fragments for 32 rows: set a = rows [n0w, n0w+16), set b = +16
  const u16* qp = Qt + (size_t)(b * NN + n0w + ln) * 64 + q * 8;
  bhalf8 qa0 = *(const bhalf8*)qp;
  bhalf8 qa1 = *(const bhalf8*)(qp + 32);
  bhalf8 qb0 = *(const bhalf8*)(qp + 16 * 64);
  bhalf8 qb1 = *(const bhalf8*)(qp + 16 * 64 + 32);
  const short ONE = 0x3F80;            // bf16 1.0
  const bhalf8 ones = {ONE, ONE, ONE, ONE, ONE, ONE, ONE, ONE};
  f32x4 oa[4], ob[4];
  f32x4 lacc_a = {0.f, 0.f, 0.f, 0.f}, lacc_b = {0.f, 0.f, 0.f, 0.f};
#pragma unroll
  for (int i = 0; i < 4; i++) { oa[i] = (f32x4){0.f,0.f,0.f,0.f}; ob[i] = (f32x4){0.f,0.f,0.f,0.f}; }
  u16* pb = pbuf + w * 2048;           // 32 rows * 64 per wave
  // staging: wave w fills LDS rows [16w,16w+16); lane covers (row 16w+(lane>>3), unit lane&7)
  int row_s = 16 * w + (lane >> 3);
  int usw = (lane & 7) ^ (row_s & 7);  // swizzled global 16B-chunk index
  const u16* kgp = Kt + ((size_t)b * NN + m_start + row_s) * 64 + usw * 8;
  const u16* vgp = Vt + (size_t)(b * 64 + row_s) * NN + m_start + usw * 8;
  u16* klds = &kbuf[w * 1024];
  u16* vlds = &vbuf[w * 1024];
  int sbase = (q ^ (ln & 7)) * 8;      // swizzled chunk offset for fragment reads

  for (int m0 = 0; m0 < CHUNKK; m0 += 64) {
    __syncthreads();                   // all waves done reading previous tile
    glds16(kgp, klds);
    glds16(kgp + 512, klds + 512);     // rows +8 (same swizzle: (r+8)&7 == r&7)
    glds16(vgp, vlds);
    glds16(vgp + (size_t)8 * NN, vlds + 512);
    kgp += 64 * 64;
    vgp += 64;
    __syncthreads();                   // staged data visible

    // S^T: lane holds m = 16*mt + 4*q + r ; n = ln (set a) / ln+16 (set b)
    f32x4 sa[4], sb[4];
#pragma unroll
    for (int mt = 0; mt < 4; mt++) {
      int krow = (16 * mt + ln) * 64;
      bhalf8 ka0 = *(const bhalf8*)&kbuf[krow + sbase];
      bhalf8 ka1 = *(const bhalf8*)&kbuf[krow + (sbase ^ 32)];
      f32x4 acc = {0.f, 0.f, 0.f, 0.f};
      acc = MFMA16(ka0, qa0, acc);
      acc = MFMA16(ka1, qa1, acc);
      sa[mt] = acc;
      f32x4 acc2 = {0.f, 0.f, 0.f, 0.f};
      acc2 = MFMA16(ka0, qb0, acc2);
      acc2 = MFMA16(ka1, qb1, acc2);
      sb[mt] = acc2;
    }
    // max-free: P = exp2(raw score), pack to bf16, store to per-wave pbuf
#pragma unroll
    for (int mt = 0; mt < 4; mt++) {
      f32x4 pa, pbv;
#pragma unroll
      for (int r = 0; r < 4; r++) {
        pa[r] = __builtin_amdgcn_exp2f(sa[mt][r]);
        pbv[r] = __builtin_amdgcn_exp2f(sb[mt][r]);
      }
      int pu = (((2 * mt + (q >> 1)) ^ (ln & 7)) << 3) + ((q & 1) << 2);  // swizzled unit + 8B sub
      u32x2 pk;
      pk[0] = pk2(pa[0], pa[1]);
      pk[1] = pk2(pa[2], pa[3]);
      *(u32x2*)&pb[ln * 64 + pu] = pk;
      pk[0] = pk2(pbv[0], pbv[1]);
      pk[1] = pk2(pbv[2], pbv[3]);
      *(u32x2*)&pb[(16 + ln) * 64 + pu] = pk;
    }
    // PV: O^T += V^T * P^T ; l via ones-A MFMA (all D rows = column sums)
#pragma unroll
    for (int s2 = 0; s2 < 2; s2++) {
      bhalf8 pfa = *(const bhalf8*)&pb[ln * 64 + (sbase ^ (32 * s2))];
      bhalf8 pfb = *(const bhalf8*)&pb[(16 + ln) * 64 + (sbase ^ (32 * s2))];
      lacc_a = MFMA16(ones, pfa, lacc_a);
      lacc_b = MFMA16(ones, pfb, lacc_b);
#pragma unroll
      for (int ct = 0; ct < 4; ct++) {
        int vrow = (16 * ct + ln) * 64;
        bhalf8 va = *(const bhalf8*)&vbuf[vrow + (sbase ^ (32 * s2))];
        oa[ct] = MFMA16(va, pfa, oa[ct]);
        ob[ct] = MFMA16(va, pfb, ob[ct]);
      }
    }
  }
  // emit partial (unnormalized O in bf16, l per row)
  size_t pbase = (size_t)blk * (128 * 64);
  int ra = 32 * w + ln, rb = ra + 16;
#pragma unroll
  for (int ct = 0; ct < 4; ct++) {
    u32x2 pka, pkb;
    pka[0] = pk2(oa[ct][0], oa[ct][1]); pka[1] = pk2(oa[ct][2], oa[ct][3]);
    pkb[0] = pk2(ob[ct][0], ob[ct][1]); pkb[1] = pk2(ob[ct][2], ob[ct][3]);
    *(u32x2*)&Opart[pbase + (size_t)ra * 64 + 16 * ct + 4 * q] = pka;
    *(u32x2*)&Opart[pbase + (size_t)rb * 64 + 16 * ct + 4 * q] = pkb;
  }
  if (q == 0) {
    float* lb_ = Lsum + (size_t)blk * 128;
    lb_[ra] = lacc_a[0];
    lb_[rb] = lacc_b[0];
  }
}

// ---------------------------------------------------------------------------
// out (fused merge + projection + residual): with max-free softmax the merge
// is a plain sum: o = (O0+O1+O2)/(l0+l1+l2) + bv ; then out = x + Wo*o + bo.
// ---------------------------------------------------------------------------
extern "C" __global__ __launch_bounds__(256, 4) void out_kernel(
    const float* __restrict__ x, const u16* __restrict__ wob, const float* __restrict__ bo,
    const u16* __restrict__ Opart, const float* __restrict__ Lsum, const float* __restrict__ bv,
    float* __restrict__ out) {
  int b = blockIdx.x / NTILES, tile = blockIdx.x % NTILES;
  int t = threadIdx.x;
  int w = t >> 6, lane = t & 63, q = lane >> 4, ln = lane & 15;
  int n0w = tile * 64 + 16 * w;
  // flash partial indexing for this lane's A-row (n = n0w + ln)
  int ptile = tile >> 1;
  int prow = (tile & 1) * 64 + 16 * w + ln;
  int p0 = (b * FTILES + ptile) * NCHUNK;
  float L = 0.f;
  float acc0[8], acc1[8];
#pragma unroll
  for (int j = 0; j < 8; j++) { acc0[j] = 0.f; acc1[j] = 0.f; }
#pragma unroll
  for (int ch = 0; ch < NCHUNK; ch++) {
    L += Lsum[(size_t)(p0 + ch) * 128 + prow];
    const u16* op = Opart + ((size_t)(p0 + ch) * 128 + prow) * 64;
    u16x8 d0 = *(const u16x8*)(op + 8 * q);
    u16x8 d1 = *(const u16x8*)(op + 32 + 8 * q);
#pragma unroll
    for (int j = 0; j < 8; j++) { acc0[j] += bf2f(d0[j]); acc1[j] += bf2f(d1[j]); }
  }
  float rl = 1.0f / L;
  union { u16x8 us; bhalf8 bh; } A0, A1;
#pragma unroll
  for (int j = 0; j < 8; j++) {
    A0.us[j] = f2bf(acc0[j] * rl + bv[8 * q + j]);
    A1.us[j] = f2bf(acc1[j] * rl + bv[32 + 8 * q + j]);
  }
  bhalf8 a0 = A0.bh, a1 = A1.bh;
#pragma unroll
  for (int ct = 0; ct < 4; ct++) {
    int wrow = (16 * ct + ln) * 64;
    bhalf8 b0 = *(const bhalf8*)&wob[wrow + q * 8];
    bhalf8 b1 = *(const bhalf8*)&wob[wrow + 32 + q * 8];
    f32x4 d = {0.f, 0.f, 0.f, 0.f};
    d = MFMA16(a0, b0, d);
    d = MFMA16(a1, b1, d);
    int co = 16 * ct + ln;
    size_t base = (size_t)(b * 64 + co) * NN + n0w + 4 * q;
    f32x4 xv = *(const f32x4*)&x[base];
    float bc = bo[co];
    f32x4 ov;
#pragma unroll
    for (int r = 0; r < 4; r++) ov[r] = xv[r] + bc + d[r];
    *(f32x4*)&out[base] = ov;
  }
}

extern "C" void kernel_launch(void* const* d_in, const int* in_sizes, int n_in,
                              void* d_out, int out_size, void* d_ws, size_t ws_size,
                              hipStream_t stream) {
  (void)in_sizes; (void)n_in; (void)out_size; (void)ws_size;
  const float* x  = (const float*)d_in[0];
  const float* wq = (const float*)d_in[1];
  const float* bq = (const float*)d_in[2];
  const float* wk = (const float*)d_in[3];
  const float* bk = (const float*)d_in[4];
  const float* wv = (const float*)d_in[5];
  const float* bv = (const float*)d_in[6];
  const float* wo = (const float*)d_in[7];
  const float* bo = (const float*)d_in[8];
  float* out = (float*)d_out;
  char* ws = (char*)d_ws;
  // workspace layout (16B aligned), ~29 MB total
  float* mean = (float*)ws;                   // 256 f32
  float* rstd = (float*)(ws + 1024);          // 256 f32
  u16* wbf = (u16*)(ws + 2048);               // 16384 bf16
  u16* Qt = (u16*)(ws + 36864);               // [B][N][64] bf16  4.72MB
  u16* Kt = Qt + (size_t)BB * NN * 64;
  u16* Vt = Kt + (size_t)BB * NN * 64;
  u16* Opart = Vt + (size_t)BB * NN * 64;     // 864 * 128*64 bf16 = 14.2MB
  float* Lsum = (float*)(Opart + (size_t)BB * FTILES * NCHUNK * 128 * 64);  // 864*128 f32
  const u16* wqb = wbf;
  const u16* wkb = wbf + 4096;
  const u16* wvb = wbf + 8192;
  const u16* wob = wbf + 12288;

  prep_kernel<<<320, 256, 0, stream>>>(x, wq, wk, wv, wo, mean, rstd, wbf);
  qkv_kernel<<<BB * NTILES, 256, 0, stream>>>(x, mean, rstd, wqb, wkb, wvb, bq, bk, Qt, Kt, Vt);
  flash_kernel<<<BB * FTILES * NCHUNK, 256, 0, stream>>>(Qt, Kt, Vt, Opart, Lsum);
  out_kernel<<<BB * NTILES, 256, 0, stream>>>(x, wob, bo, Opart, Lsum, bv, out);
}

// Round 6
// 220.522 us; speedup vs baseline: 1.7269x; 1.0010x over previous
//
#include <hip/hip_runtime.h>
#include <stdint.h>

#define BB 4
#define CCH 64
#define NN 9216      // 96*96
#define NTILES 144   // NN/64  (qkv/out kernels: 64-wide n tiles)
#define FTILES 72    // NN/128 (flash: 128 Q-rows per block)
#define NCHUNK 3     // split-K chunks (grid 864 <= 1024 resident capacity)
#define CHUNKK 3072  // NN/NCHUNK keys per chunk

typedef unsigned short u16;
typedef __attribute__((ext_vector_type(8))) short bhalf8;   // 8 bf16 lanes of an MFMA operand
typedef __attribute__((ext_vector_type(4))) float f32x4;
typedef __attribute__((ext_vector_type(4))) u16 u16x4;
typedef __attribute__((ext_vector_type(8))) u16 u16x8;
typedef __attribute__((ext_vector_type(2))) unsigned int u32x2;

#define MFMA16(a, b, c) __builtin_amdgcn_mfma_f32_16x16x32_bf16((a), (b), (c), 0, 0, 0)

static __device__ __forceinline__ u16 f2bf(float f) {
  union { float f; unsigned u; } v; v.f = f;
  return (u16)((v.u + 0x7fffu + ((v.u >> 16) & 1u)) >> 16);  // RNE
}
static __device__ __forceinline__ float bf2f(u16 h) {
  union { unsigned u; float f; } v; v.u = ((unsigned)h) << 16; return v.f;
}
// pack two f32 -> (bf16(hi)<<16)|bf16(lo), round-half-up, 3 VALU ops total
static __device__ __forceinline__ unsigned pk2(float lo, float hi) {
  unsigned a = __float_as_uint(hi) + 0x8000u;
  unsigned b = __float_as_uint(lo) + 0x8000u;
  return __builtin_amdgcn_perm(a, b, 0x07060302u);  // bytes {a3,a2,b3,b2}
}
// async global->LDS, 16B per lane; lds dest = wave-uniform base + lane*16
static __device__ __forceinline__ void glds16(const void* g, void* l) {
  __builtin_amdgcn_global_load_lds(
      (const __attribute__((address_space(1))) unsigned int*)g,
      (__attribute__((address_space(3))) unsigned int*)l, 16, 0, 0);
}

// ---------------------------------------------------------------------------
// prep: blocks [0,256): per-(b,c) mean/rstd over 9216 spatial elems.
//       blocks [256,320): convert wq,wk,wv,wo (4*4096 f32) to bf16.
// ---------------------------------------------------------------------------
extern "C" __global__ __launch_bounds__(256) void prep_kernel(
    const float* __restrict__ x,
    const float* __restrict__ wq, const float* __restrict__ wk,
    const float* __restrict__ wv, const float* __restrict__ wo,
    float* __restrict__ mean, float* __restrict__ rstd, u16* __restrict__ wbf) {
  if (blockIdx.x >= 256) {
    int i = (blockIdx.x - 256) * 256 + threadIdx.x;  // 0..16383
    const float* src = (i < 4096) ? wq : (i < 8192) ? wk : (i < 12288) ? wv : wo;
    wbf[i] = f2bf(src[i & 4095]);
    return;
  }
  int idx = blockIdx.x;
  const float* p = x + (size_t)idx * NN;
  float s = 0.f, ss = 0.f;
  for (int i = threadIdx.x; i < NN; i += 256) { float v = p[i]; s += v; ss += v * v; }
#pragma unroll
  for (int o = 32; o > 0; o >>= 1) { s += __shfl_xor(s, o, 64); ss += __shfl_xor(ss, o, 64); }
  __shared__ float ls[4], lss[4];
  int w = threadIdx.x >> 6;
  if ((threadIdx.x & 63) == 0) { ls[w] = s; lss[w] = ss; }
  __syncthreads();
  if (threadIdx.x == 0) {
    s = ls[0] + ls[1] + ls[2] + ls[3];
    ss = lss[0] + lss[1] + lss[2] + lss[3];
    float m = s * (1.f / NN);
    float var = ss * (1.f / NN) - m * m;
    mean[idx] = m;
    rstd[idx] = rsqrtf(var + 1e-5f);
  }
}

// ---------------------------------------------------------------------------
// qkv: fused instance-norm + 1x1 convs via MFMA.
// Qt,Kt = [B][N][64] bf16 (Q pre-scaled by 0.125*log2e), Vt = [B][64][N] bf16.
// hbuf staged with b64 packed writes (thread = one n, 4 consecutive c per rep).
// ---------------------------------------------------------------------------
extern "C" __global__ __launch_bounds__(256, 4) void qkv_kernel(
    const float* __restrict__ x,
    const float* __restrict__ mean, const float* __restrict__ rstd,
    const u16* __restrict__ wqb, const u16* __restrict__ wkb, const u16* __restrict__ wvb,
    const float* __restrict__ bq, const float* __restrict__ bk,
    u16* __restrict__ Qt, u16* __restrict__ Kt, u16* __restrict__ Vt) {
  __shared__ u16 hbuf[64 * 72];  // [n_local][c], padded rows
  int b = blockIdx.x / NTILES, tile = blockIdx.x % NTILES;
  int n0 = tile * 64;
  int t = threadIdx.x;
  int w = t >> 6, lane = t & 63, q = lane >> 4, ln = lane & 15;
  const float QSCALE = 0.125f * 1.44269504088896340736f;  // C^-0.5 * log2(e)
  const float* mb = mean + b * 64;
  const float* rb_ = rstd + b * 64;
  int nloc = lane;  // note: per-wave n is lane; c groups are wave-uniform
#pragma unroll
  for (int rep = 0; rep < 4; rep++) {
    int c0 = 16 * w + 4 * rep;  // wave-uniform
    float h0 = (x[(size_t)(b * 64 + c0 + 0) * NN + n0 + nloc] - mb[c0 + 0]) * rb_[c0 + 0];
    float h1 = (x[(size_t)(b * 64 + c0 + 1) * NN + n0 + nloc] - mb[c0 + 1]) * rb_[c0 + 1];
    float h2 = (x[(size_t)(b * 64 + c0 + 2) * NN + n0 + nloc] - mb[c0 + 2]) * rb_[c0 + 2];
    float h3 = (x[(size_t)(b * 64 + c0 + 3) * NN + n0 + nloc] - mb[c0 + 3]) * rb_[c0 + 3];
    u32x2 hp;
    hp[0] = pk2(h0, h1);
    hp[1] = pk2(h2, h3);
    *(u32x2*)&hbuf[nloc * 72 + c0] = hp;
  }
  __syncthreads();
  int hrow = (16 * w + ln) * 72;
  bhalf8 hb0 = *(const bhalf8*)&hbuf[hrow + q * 8];
  bhalf8 hb1 = *(const bhalf8*)&hbuf[hrow + 32 + q * 8];
  size_t nrow = (size_t)(b * NN + n0 + 16 * w + ln) * 64;
  // ---- Q (transposed orientation: reg quad = 4 consecutive channels) ----
#pragma unroll
  for (int ct = 0; ct < 4; ct++) {
    int wrow = (16 * ct + ln) * 64;
    bhalf8 a0 = *(const bhalf8*)&wqb[wrow + q * 8];
    bhalf8 a1 = *(const bhalf8*)&wqb[wrow + 32 + q * 8];
    f32x4 d = {0.f, 0.f, 0.f, 0.f};
    d = MFMA16(a0, hb0, d);
    d = MFMA16(a1, hb1, d);
    f32x4 b4 = *(const f32x4*)&bq[16 * ct + 4 * q];
    u16x4 pk;
#pragma unroll
    for (int r = 0; r < 4; r++) pk[r] = f2bf((d[r] + b4[r]) * QSCALE);
    *(u16x4*)&Qt[nrow + 16 * ct + 4 * q] = pk;
  }
  // ---- K ----
#pragma unroll
  for (int ct = 0; ct < 4; ct++) {
    int wrow = (16 * ct + ln) * 64;
    bhalf8 a0 = *(const bhalf8*)&wkb[wrow + q * 8];
    bhalf8 a1 = *(const bhalf8*)&wkb[wrow + 32 + q * 8];
    f32x4 d = {0.f, 0.f, 0.f, 0.f};
    d = MFMA16(a0, hb0, d);
    d = MFMA16(a1, hb1, d);
    f32x4 b4 = *(const f32x4*)&bk[16 * ct + 4 * q];
    u16x4 pk;
#pragma unroll
    for (int r = 0; r < 4; r++) pk[r] = f2bf(d[r] + b4[r]);
    *(u16x4*)&Kt[nrow + 16 * ct + 4 * q] = pk;
  }
  // ---- V (normal orientation; bv folded into epilogue) ----
#pragma unroll
  for (int ct = 0; ct < 4; ct++) {
    int wrow = (16 * ct + ln) * 64;
    bhalf8 b0 = *(const bhalf8*)&wvb[wrow + q * 8];
    bhalf8 b1 = *(const bhalf8*)&wvb[wrow + 32 + q * 8];
    f32x4 d = {0.f, 0.f, 0.f, 0.f};
    d = MFMA16(hb0, b0, d);
    d = MFMA16(hb1, b1, d);
    u16x4 pk;
#pragma unroll
    for (int r = 0; r < 4; r++) pk[r] = f2bf(d[r]);
    *(u16x4*)&Vt[(size_t)(b * 64 + 16 * ct + ln) * NN + n0 + 16 * w + 4 * q] = pk;
  }
}

// ---------------------------------------------------------------------------
// flash: split-K attention, max-free softmax, SINGLE-BARRIER double-buffered
// K-loop. DMA for tile i+1 is issued right after the barrier; the compiler's
// vmcnt(0) drain at the NEXT barrier then waits on a load that had a full
// compute iteration in flight -> no drain stall (fixes the m97-style stall).
// Per-iter work split into two 32-key phases reusing a 2KB/wave pbuf.
// LDS = 2x8(K) + 2x8(V) + 8(P) = 40KB -> 4 blocks/CU; grid 864 co-resident.
// ---------------------------------------------------------------------------
extern "C" __global__ __launch_bounds__(256, 4) void flash_kernel(
    const u16* __restrict__ Qt, const u16* __restrict__ Kt, const u16* __restrict__ Vt,
    u16* __restrict__ Opart, float* __restrict__ Lsum) {
  __shared__ u16 kbuf[2][64 * 64];     // [m_local][c], 16B units swizzled by (row&7)
  __shared__ u16 vbuf[2][64 * 64];     // [c][m_local], 16B units swizzled by (row&7)
  __shared__ u16 pbuf[4][16 * 64];     // per-wave [n_local(16)][32 keys x 2 sets], swizzled
  int blk = blockIdx.x;
  int b = blk / (FTILES * NCHUNK);
  int rem = blk % (FTILES * NCHUNK);
  int tile = rem / NCHUNK, chunk = rem % NCHUNK;
  int m_start = chunk * CHUNKK;
  int t = threadIdx.x;
  int w = t >> 6, lane = t & 63, q = lane >> 4, ln = lane & 15;
  int n0w = tile * 128 + 32 * w;
  // Q fragments for 32 rows: set a = rows [n0w, n0w+16), set b = +16
  const u16* qp = Qt + (size_t)(b * NN + n0w + ln) * 64 + q * 8;
  bhalf8 qa0 = *(const bhalf8*)qp;
  bhalf8 qa1 = *(const bhalf8*)(qp + 32);
  bhalf8 qb0 = *(const bhalf8*)(qp + 16 * 64);
  bhalf8 qb1 = *(const bhalf8*)(qp + 16 * 64 + 32);
  const short ONE = 0x3F80;            // bf16 1.0
  const bhalf8 ones = {ONE, ONE, ONE, ONE, ONE, ONE, ONE, ONE};
  f32x4 oa[4], ob[4];
  f32x4 lacc_a = {0.f, 0.f, 0.f, 0.f}, lacc_b = {0.f, 0.f, 0.f, 0.f};
#pragma unroll
  for (int i = 0; i < 4; i++) { oa[i] = (f32x4){0.f,0.f,0.f,0.f}; ob[i] = (f32x4){0.f,0.f,0.f,0.f}; }
  u16* pw = pbuf[w];
  // staging: wave w fills LDS rows [16w,16w+16); lane covers (row 16w+(lane>>3), unit lane&7)
  int row_s = 16 * w + (lane >> 3);
  int usw = (lane & 7) ^ (row_s & 7);  // swizzled global 16B-chunk index
  const u16* kgp = Kt + ((size_t)b * NN + m_start + row_s) * 64 + usw * 8;
  const u16* vgp = Vt + (size_t)(b * 64 + row_s) * NN + m_start + usw * 8;
  int sbase = (q ^ (ln & 7)) * 8;      // swizzled chunk offset for fragment reads
  const int NIT = CHUNKK / 64;         // 48

  // prologue: DMA tile 0 -> buffer 0
  {
    u16* kl = &kbuf[0][w * 1024];
    u16* vl = &vbuf[0][w * 1024];
    glds16(kgp, kl); glds16(kgp + 512, kl + 512);
    glds16(vgp, vl); glds16(vgp + (size_t)8 * NN, vl + 512);
    kgp += 4096; vgp += 64;
  }

#pragma unroll 2
  for (int i = 0; i < NIT; i++) {
    __syncthreads();                   // per-wave vmcnt drain (tile i, full iter in flight) + sync
    if (i + 1 < NIT) {                 // prefetch tile i+1 into the other buffer
      u16* kl = &kbuf[(i + 1) & 1][w * 1024];
      u16* vl = &vbuf[(i + 1) & 1][w * 1024];
      glds16(kgp, kl); glds16(kgp + 512, kl + 512);
      glds16(vgp, vl); glds16(vgp + (size_t)8 * NN, vl + 512);
      kgp += 4096; vgp += 64;
    }
    const u16* kb = kbuf[i & 1];
    const u16* vb = vbuf[i & 1];
    // two 32-key phases; per-wave pbuf reused each phase
#pragma unroll
    for (int p = 0; p < 2; p++) {
      f32x4 s[4];  // [2*lm + set]; lm = local mt, set 0=a (rows ln), 1=b (rows ln+16)
#pragma unroll
      for (int lm = 0; lm < 2; lm++) {
        int mt = 2 * p + lm;
        int krow = (16 * mt + ln) * 64;
        bhalf8 ka0 = *(const bhalf8*)&kb[krow + sbase];
        bhalf8 ka1 = *(const bhalf8*)&kb[krow + (sbase ^ 32)];
        f32x4 acc = {0.f, 0.f, 0.f, 0.f};
        acc = MFMA16(ka0, qa0, acc);
        acc = MFMA16(ka1, qa1, acc);
        s[2 * lm] = acc;
        f32x4 acc2 = {0.f, 0.f, 0.f, 0.f};
        acc2 = MFMA16(ka0, qb0, acc2);
        acc2 = MFMA16(ka1, qb1, acc2);
        s[2 * lm + 1] = acc2;
      }
      // max-free: P = exp2(raw score); pack; write to per-wave pbuf
#pragma unroll
      for (int lm = 0; lm < 2; lm++) {
        f32x4 pa, pbv;
#pragma unroll
        for (int r = 0; r < 4; r++) {
          pa[r] = __builtin_amdgcn_exp2f(s[2 * lm][r]);
          pbv[r] = __builtin_amdgcn_exp2f(s[2 * lm + 1][r]);
        }
        int ua = (2 * lm + (q >> 1)) ^ (ln & 7);        // set a: logical units 0..3
        int ub = (4 + 2 * lm + (q >> 1)) ^ (ln & 7);    // set b: logical units 4..7
        u32x2 pka, pkb;
        pka[0] = pk2(pa[0], pa[1]);  pka[1] = pk2(pa[2], pa[3]);
        pkb[0] = pk2(pbv[0], pbv[1]); pkb[1] = pk2(pbv[2], pbv[3]);
        *(u32x2*)&pw[ln * 64 + ua * 8 + (q & 1) * 4] = pka;
        *(u32x2*)&pw[ln * 64 + ub * 8 + (q & 1) * 4] = pkb;
      }
      bhalf8 pfa = *(const bhalf8*)&pw[ln * 64 + ((q ^ (ln & 7)) * 8)];
      bhalf8 pfb = *(const bhalf8*)&pw[ln * 64 + (((4 + q) ^ (ln & 7)) * 8)];
      lacc_a = MFMA16(ones, pfa, lacc_a);
      lacc_b = MFMA16(ones, pfb, lacc_b);
#pragma unroll
      for (int ct = 0; ct < 4; ct++) {
        int vrow = (16 * ct + ln) * 64;
        bhalf8 va = *(const bhalf8*)&vb[vrow + (sbase ^ (32 * p))];
        oa[ct] = MFMA16(va, pfa, oa[ct]);
        ob[ct] = MFMA16(va, pfb, ob[ct]);
      }
    }
  }
  // emit partial (unnormalized O in bf16, l per row)
  size_t pbase = (size_t)blk * (128 * 64);
  int ra = 32 * w + ln, rb = ra + 16;
#pragma unroll
  for (int ct = 0; ct < 4; ct++) {
    u32x2 pka, pkb;
    pka[0] = pk2(oa[ct][0], oa[ct][1]); pka[1] = pk2(oa[ct][2], oa[ct][3]);
    pkb[0] = pk2(ob[ct][0], ob[ct][1]); pkb[1] = pk2(ob[ct][2], ob[ct][3]);
    *(u32x2*)&Opart[pbase + (size_t)ra * 64 + 16 * ct + 4 * q] = pka;
    *(u32x2*)&Opart[pbase + (size_t)rb * 64 + 16 * ct + 4 * q] = pkb;
  }
  if (q == 0) {
    float* lb_ = Lsum + (size_t)blk * 128;
    lb_[ra] = lacc_a[0];
    lb_[rb] = lacc_b[0];
  }
}

// ---------------------------------------------------------------------------
// out (fused merge + projection + residual): with max-free softmax the merge
// is a plain sum: o = (O0+O1+O2)/(l0+l1+l2) + bv ; then out = x + Wo*o + bo.
// ---------------------------------------------------------------------------
extern "C" __global__ __launch_bounds__(256, 4) void out_kernel(
    const float* __restrict__ x, const u16* __restrict__ wob, const float* __restrict__ bo,
    const u16* __restrict__ Opart, const float* __restrict__ Lsum, const float* __restrict__ bv,
    float* __restrict__ out) {
  int b = blockIdx.x / NTILES, tile = blockIdx.x % NTILES;
  int t = threadIdx.x;
  int w = t >> 6, lane = t & 63, q = lane >> 4, ln = lane & 15;
  int n0w = tile * 64 + 16 * w;
  // flash partial indexing for this lane's A-row (n = n0w + ln)
  int ptile = tile >> 1;
  int prow = (tile & 1) * 64 + 16 * w + ln;
  int p0 = (b * FTILES + ptile) * NCHUNK;
  float L = 0.f;
  float acc0[8], acc1[8];
#pragma unroll
  for (int j = 0; j < 8; j++) { acc0[j] = 0.f; acc1[j] = 0.f; }
#pragma unroll
  for (int ch = 0; ch < NCHUNK; ch++) {
    L += Lsum[(size_t)(p0 + ch) * 128 + prow];
    const u16* op = Opart + ((size_t)(p0 + ch) * 128 + prow) * 64;
    u16x8 d0 = *(const u16x8*)(op + 8 * q);
    u16x8 d1 = *(const u16x8*)(op + 32 + 8 * q);
#pragma unroll
    for (int j = 0; j < 8; j++) { acc0[j] += bf2f(d0[j]); acc1[j] += bf2f(d1[j]); }
  }
  float rl = 1.0f / L;
  union { u16x8 us; bhalf8 bh; } A0, A1;
#pragma unroll
  for (int j = 0; j < 8; j++) {
    A0.us[j] = f2bf(acc0[j] * rl + bv[8 * q + j]);
    A1.us[j] = f2bf(acc1[j] * rl + bv[32 + 8 * q + j]);
  }
  bhalf8 a0 = A0.bh, a1 = A1.bh;
#pragma unroll
  for (int ct = 0; ct < 4; ct++) {
    int wrow = (16 * ct + ln) * 64;
    bhalf8 b0 = *(const bhalf8*)&wob[wrow + q * 8];
    bhalf8 b1 = *(const bhalf8*)&wob[wrow + 32 + q * 8];
    f32x4 d = {0.f, 0.f, 0.f, 0.f};
    d = MFMA16(a0, b0, d);
    d = MFMA16(a1, b1, d);
    int co = 16 * ct + ln;
    size_t base = (size_t)(b * 64 + co) * NN + n0w + 4 * q;
    f32x4 xv = *(const f32x4*)&x[base];
    float bc = bo[co];
    f32x4 ov;
#pragma unroll
    for (int r = 0; r < 4; r++) ov[r] = xv[r] + bc + d[r];
    *(f32x4*)&out[base] = ov;
  }
}

extern "C" void kernel_launch(void* const* d_in, const int* in_sizes, int n_in,
                              void* d_out, int out_size, void* d_ws, size_t ws_size,
                              hipStream_t stream) {
  (void)in_sizes; (void)n_in; (void)out_size; (void)ws_size;
  const float* x  = (const float*)d_in[0];
  const float* wq = (const float*)d_in[1];
  const float* bq = (const float*)d_in[2];
  const float* wk = (const float*)d_in[3];
  const float* bk = (const float*)d_in[4];
  const float* wv = (const float*)d_in[5];
  const float* bv = (const float*)d_in[6];
  const float* wo = (const float*)d_in[7];
  const float* bo = (const float*)d_in[8];
  float* out = (float*)d_out;
  char* ws = (char*)d_ws;
  // workspace layout (16B aligned), ~29 MB total
  float* mean = (float*)ws;                   // 256 f32
  float* rstd = (float*)(ws + 1024);          // 256 f32
  u16* wbf = (u16*)(ws + 2048);               // 16384 bf16
  u16* Qt = (u16*)(ws + 36864);               // [B][N][64] bf16  4.72MB
  u16* Kt = Qt + (size_t)BB * NN * 64;
  u16* Vt = Kt + (size_t)BB * NN * 64;
  u16* Opart = Vt + (size_t)BB * NN * 64;     // 864 * 128*64 bf16 = 14.2MB
  float* Lsum = (float*)(Opart + (size_t)BB * FTILES * NCHUNK * 128 * 64);  // 864*128 f32
  const u16* wqb = wbf;
  const u16* wkb = wbf + 4096;
  const u16* wvb = wbf + 8192;
  const u16* wob = wbf + 12288;

  prep_kernel<<<320, 256, 0, stream>>>(x, wq, wk, wv, wo, mean, rstd, wbf);
  qkv_kernel<<<BB * NTILES, 256, 0, stream>>>(x, mean, rstd, wqb, wkb, wvb, bq, bk, Qt, Kt, Vt);
  flash_kernel<<<BB * FTILES * NCHUNK, 256, 0, stream>>>(Qt, Kt, Vt, Opart, Lsum);
  out_kernel<<<BB * NTILES, 256, 0, stream>>>(x, wob, bo, Opart, Lsum, bv, out);
}

// Round 7
// 213.127 us; speedup vs baseline: 1.7869x; 1.0347x over previous
//
#include <hip/hip_runtime.h>
#include <stdint.h>

#define BB 4
#define CCH 64
#define NN 9216      // 96*96
#define NTILES 144   // NN/64  (qkv/out kernels: 64-wide n tiles)
#define FTILES 36    // NN/256 (flash: 256 Q-rows per block, 64 per wave)
#define NCHUNK 5     // split-K chunks, uneven (29,29,29,29,28 iters of 64 keys)

typedef unsigned short u16;
typedef __attribute__((ext_vector_type(8))) short bhalf8;   // 8 bf16 lanes of an MFMA operand
typedef __attribute__((ext_vector_type(4))) float f32x4;
typedef __attribute__((ext_vector_type(4))) u16 u16x4;
typedef __attribute__((ext_vector_type(8))) u16 u16x8;
typedef __attribute__((ext_vector_type(2))) unsigned int u32x2;

#define MFMA16(a, b, c) __builtin_amdgcn_mfma_f32_16x16x32_bf16((a), (b), (c), 0, 0, 0)

static __device__ __forceinline__ u16 f2bf(float f) {
  union { float f; unsigned u; } v; v.f = f;
  return (u16)((v.u + 0x7fffu + ((v.u >> 16) & 1u)) >> 16);  // RNE
}
static __device__ __forceinline__ float bf2f(u16 h) {
  union { unsigned u; float f; } v; v.u = ((unsigned)h) << 16; return v.f;
}
// pack two f32 -> (bf16(hi)<<16)|bf16(lo), round-half-up, 3 VALU ops total
static __device__ __forceinline__ unsigned pk2(float lo, float hi) {
  unsigned a = __float_as_uint(hi) + 0x8000u;
  unsigned b = __float_as_uint(lo) + 0x8000u;
  return __builtin_amdgcn_perm(a, b, 0x07060302u);  // bytes {a3,a2,b3,b2}
}
// async global->LDS, 16B per lane; lds dest = wave-uniform base + lane*16
static __device__ __forceinline__ void glds16(const void* g, void* l) {
  __builtin_amdgcn_global_load_lds(
      (const __attribute__((address_space(1))) unsigned int*)g,
      (__attribute__((address_space(3))) unsigned int*)l, 16, 0, 0);
}

// ---------------------------------------------------------------------------
// prep: blocks [0,256): per-(b,c) mean/rstd over 9216 spatial elems.
//       blocks [256,320): convert wq,wk,wv,wo (4*4096 f32) to bf16.
// ---------------------------------------------------------------------------
extern "C" __global__ __launch_bounds__(256) void prep_kernel(
    const float* __restrict__ x,
    const float* __restrict__ wq, const float* __restrict__ wk,
    const float* __restrict__ wv, const float* __restrict__ wo,
    float* __restrict__ mean, float* __restrict__ rstd, u16* __restrict__ wbf) {
  if (blockIdx.x >= 256) {
    int i = (blockIdx.x - 256) * 256 + threadIdx.x;  // 0..16383
    const float* src = (i < 4096) ? wq : (i < 8192) ? wk : (i < 12288) ? wv : wo;
    wbf[i] = f2bf(src[i & 4095]);
    return;
  }
  int idx = blockIdx.x;
  const float* p = x + (size_t)idx * NN;
  float s = 0.f, ss = 0.f;
  for (int i = threadIdx.x; i < NN; i += 256) { float v = p[i]; s += v; ss += v * v; }
#pragma unroll
  for (int o = 32; o > 0; o >>= 1) { s += __shfl_xor(s, o, 64); ss += __shfl_xor(ss, o, 64); }
  __shared__ float ls[4], lss[4];
  int w = threadIdx.x >> 6;
  if ((threadIdx.x & 63) == 0) { ls[w] = s; lss[w] = ss; }
  __syncthreads();
  if (threadIdx.x == 0) {
    s = ls[0] + ls[1] + ls[2] + ls[3];
    ss = lss[0] + lss[1] + lss[2] + lss[3];
    float m = s * (1.f / NN);
    float var = ss * (1.f / NN) - m * m;
    mean[idx] = m;
    rstd[idx] = rsqrtf(var + 1e-5f);
  }
}

// ---------------------------------------------------------------------------
// qkv: fused instance-norm + 1x1 convs via MFMA.
// Qt,Kt = [B][N][64] bf16 (Q pre-scaled by 0.125*log2e), Vt = [B][64][N] bf16.
// ---------------------------------------------------------------------------
extern "C" __global__ __launch_bounds__(256, 4) void qkv_kernel(
    const float* __restrict__ x,
    const float* __restrict__ mean, const float* __restrict__ rstd,
    const u16* __restrict__ wqb, const u16* __restrict__ wkb, const u16* __restrict__ wvb,
    const float* __restrict__ bq, const float* __restrict__ bk,
    u16* __restrict__ Qt, u16* __restrict__ Kt, u16* __restrict__ Vt) {
  __shared__ u16 hbuf[64 * 72];  // [n_local][c], padded rows
  int b = blockIdx.x / NTILES, tile = blockIdx.x % NTILES;
  int n0 = tile * 64;
  int t = threadIdx.x;
  int w = t >> 6, lane = t & 63, q = lane >> 4, ln = lane & 15;
  const float QSCALE = 0.125f * 1.44269504088896340736f;  // C^-0.5 * log2(e)
  const float* mb = mean + b * 64;
  const float* rb_ = rstd + b * 64;
  int nloc = lane;
#pragma unroll
  for (int rep = 0; rep < 4; rep++) {
    int c0 = 16 * w + 4 * rep;  // wave-uniform
    float h0 = (x[(size_t)(b * 64 + c0 + 0) * NN + n0 + nloc] - mb[c0 + 0]) * rb_[c0 + 0];
    float h1 = (x[(size_t)(b * 64 + c0 + 1) * NN + n0 + nloc] - mb[c0 + 1]) * rb_[c0 + 1];
    float h2 = (x[(size_t)(b * 64 + c0 + 2) * NN + n0 + nloc] - mb[c0 + 2]) * rb_[c0 + 2];
    float h3 = (x[(size_t)(b * 64 + c0 + 3) * NN + n0 + nloc] - mb[c0 + 3]) * rb_[c0 + 3];
    u32x2 hp;
    hp[0] = pk2(h0, h1);
    hp[1] = pk2(h2, h3);
    *(u32x2*)&hbuf[nloc * 72 + c0] = hp;
  }
  __syncthreads();
  int hrow = (16 * w + ln) * 72;
  bhalf8 hb0 = *(const bhalf8*)&hbuf[hrow + q * 8];
  bhalf8 hb1 = *(const bhalf8*)&hbuf[hrow + 32 + q * 8];
  size_t nrow = (size_t)(b * NN + n0 + 16 * w + ln) * 64;
  // ---- Q (transposed orientation: reg quad = 4 consecutive channels) ----
#pragma unroll
  for (int ct = 0; ct < 4; ct++) {
    int wrow = (16 * ct + ln) * 64;
    bhalf8 a0 = *(const bhalf8*)&wqb[wrow + q * 8];
    bhalf8 a1 = *(const bhalf8*)&wqb[wrow + 32 + q * 8];
    f32x4 d = {0.f, 0.f, 0.f, 0.f};
    d = MFMA16(a0, hb0, d);
    d = MFMA16(a1, hb1, d);
    f32x4 b4 = *(const f32x4*)&bq[16 * ct + 4 * q];
    u16x4 pk;
#pragma unroll
    for (int r = 0; r < 4; r++) pk[r] = f2bf((d[r] + b4[r]) * QSCALE);
    *(u16x4*)&Qt[nrow + 16 * ct + 4 * q] = pk;
  }
  // ---- K ----
#pragma unroll
  for (int ct = 0; ct < 4; ct++) {
    int wrow = (16 * ct + ln) * 64;
    bhalf8 a0 = *(const bhalf8*)&wkb[wrow + q * 8];
    bhalf8 a1 = *(const bhalf8*)&wkb[wrow + 32 + q * 8];
    f32x4 d = {0.f, 0.f, 0.f, 0.f};
    d = MFMA16(a0, hb0, d);
    d = MFMA16(a1, hb1, d);
    f32x4 b4 = *(const f32x4*)&bk[16 * ct + 4 * q];
    u16x4 pk;
#pragma unroll
    for (int r = 0; r < 4; r++) pk[r] = f2bf(d[r] + b4[r]);
    *(u16x4*)&Kt[nrow + 16 * ct + 4 * q] = pk;
  }
  // ---- V (normal orientation; bv folded into epilogue) ----
#pragma unroll
  for (int ct = 0; ct < 4; ct++) {
    int wrow = (16 * ct + ln) * 64;
    bhalf8 b0 = *(const bhalf8*)&wvb[wrow + q * 8];
    bhalf8 b1 = *(const bhalf8*)&wvb[wrow + 32 + q * 8];
    f32x4 d = {0.f, 0.f, 0.f, 0.f};
    d = MFMA16(hb0, b0, d);
    d = MFMA16(hb1, b1, d);
    u16x4 pk;
#pragma unroll
    for (int r = 0; r < 4; r++) pk[r] = f2bf(d[r]);
    *(u16x4*)&Vt[(size_t)(b * 64 + 16 * ct + ln) * NN + n0 + 16 * w + 4 * q] = pk;
  }
}

// ---------------------------------------------------------------------------
// flash: split-K attention, max-free softmax, 64 Q-ROWS PER WAVE (4 sets).
// K/V fragment LDS reads amortized over 2x MFMA work vs 32-row version
// (LDS data pipe was the measured bottleneck at ~70% busy in R6).
// Block = 4 waves x 64 rows = 256 Q-rows; one of 5 uneven key-chunks.
// LDS = 2x8K + 2x8V + 16P = 48KB -> 3 blocks/CU; launch_bounds(256,3)
// gives ~170 VGPR budget (peak live ~145, no spill).
// Grid 720 <= 768 capacity -> single scheduling round, 93% balance.
// ---------------------------------------------------------------------------
extern "C" __global__ __launch_bounds__(256, 3) void flash_kernel(
    const u16* __restrict__ Qt, const u16* __restrict__ Kt, const u16* __restrict__ Vt,
    u16* __restrict__ Opart, float* __restrict__ Lsum) {
  __shared__ u16 kbuf[2][64 * 64];     // [m_local][c], 16B units swizzled by (row&7)
  __shared__ u16 vbuf[2][64 * 64];     // [c][m_local], 16B units swizzled by (row&7)
  __shared__ u16 pbuf[4][64 * 32];     // per-wave [n_local(64)][32 keys], 4-unit XOR swizzle
  int blk = blockIdx.x;
  int b = blk / (FTILES * NCHUNK);
  int rem = blk % (FTILES * NCHUNK);
  int tile = rem / NCHUNK, chunk = rem % NCHUNK;
  int it0 = chunk * 28 + (chunk < 4 ? chunk : 4);   // 0,29,58,87,116
  int nit = 28 + (chunk < 4 ? 1 : 0);               // 29,29,29,29,28
  int m_start = it0 * 64;
  int t = threadIdx.x;
  int w = t >> 6, lane = t & 63, q = lane >> 4, ln = lane & 15;
  int n0w = tile * 256 + 64 * w;
  // Q fragments for 4 sets of 16 rows each
  bhalf8 qf0[4], qf1[4];
#pragma unroll
  for (int s = 0; s < 4; s++) {
    const u16* qp = Qt + (size_t)(b * NN + n0w + 16 * s + ln) * 64 + q * 8;
    qf0[s] = *(const bhalf8*)qp;
    qf1[s] = *(const bhalf8*)(qp + 32);
  }
  const short ONE = 0x3F80;            // bf16 1.0
  const bhalf8 ones = {ONE, ONE, ONE, ONE, ONE, ONE, ONE, ONE};
  f32x4 o[4][4];                       // [ct][set]
  f32x4 lacc[4];
#pragma unroll
  for (int ct = 0; ct < 4; ct++) {
    lacc[ct] = (f32x4){0.f, 0.f, 0.f, 0.f};
#pragma unroll
    for (int s = 0; s < 4; s++) o[ct][s] = (f32x4){0.f, 0.f, 0.f, 0.f};
  }
  u16* pw = pbuf[w];
  // staging: wave w fills LDS rows [16w,16w+16); lane covers (row 16w+(lane>>3), unit lane&7)
  int row_s = 16 * w + (lane >> 3);
  int usw = (lane & 7) ^ (row_s & 7);  // swizzled global 16B-chunk index
  const u16* kgp = Kt + ((size_t)b * NN + m_start + row_s) * 64 + usw * 8;
  const u16* vgp = Vt + (size_t)(b * 64 + row_s) * NN + m_start + usw * 8;
  int sbase = (q ^ (ln & 7)) * 8;      // swizzled chunk offset for K/V fragment reads

  // prologue: DMA tile 0 -> buffer 0
  {
    u16* kl = &kbuf[0][w * 1024];
    u16* vl = &vbuf[0][w * 1024];
    glds16(kgp, kl); glds16(kgp + 512, kl + 512);
    glds16(vgp, vl); glds16(vgp + (size_t)8 * NN, vl + 512);
    kgp += 4096; vgp += 64;
  }

  for (int i = 0; i < nit; i++) {
    __syncthreads();
    if (i + 1 < nit) {                 // prefetch tile i+1 into the other buffer
      u16* kl = &kbuf[(i + 1) & 1][w * 1024];
      u16* vl = &vbuf[(i + 1) & 1][w * 1024];
      glds16(kgp, kl); glds16(kgp + 512, kl + 512);
      glds16(vgp, vl); glds16(vgp + (size_t)8 * NN, vl + 512);
      kgp += 4096; vgp += 64;
    }
    const u16* kb = kbuf[i & 1];
    const u16* vb = vbuf[i & 1];
#pragma unroll
    for (int p = 0; p < 2; p++) {      // two 32-key phases
#pragma unroll
      for (int lm = 0; lm < 2; lm++) { // 16 keys each
        int krow = (16 * (2 * p + lm) + ln) * 64;
        bhalf8 ka0 = *(const bhalf8*)&kb[krow + sbase];
        bhalf8 ka1 = *(const bhalf8*)&kb[krow + (sbase ^ 32)];
        int uw = (((2 * lm + (q >> 1)) ^ ((ln >> 1) & 3)) << 3) + ((q & 1) << 2);
#pragma unroll
        for (int s = 0; s < 4; s++) {
          f32x4 acc = {0.f, 0.f, 0.f, 0.f};
          acc = MFMA16(ka0, qf0[s], acc);
          acc = MFMA16(ka1, qf1[s], acc);
          f32x4 pv;
#pragma unroll
          for (int r = 0; r < 4; r++) pv[r] = __builtin_amdgcn_exp2f(acc[r]);
          u32x2 pk;
          pk[0] = pk2(pv[0], pv[1]);
          pk[1] = pk2(pv[2], pv[3]);
          *(u32x2*)&pw[(16 * s + ln) * 32 + uw] = pk;
        }
      }
      // PV for this 32-key phase: O^T += V^T * P^T ; l via ones-A MFMA
      int ur = ((q ^ ((ln >> 1) & 3)) << 3);
      bhalf8 pf[4];
#pragma unroll
      for (int s = 0; s < 4; s++) pf[s] = *(const bhalf8*)&pw[(16 * s + ln) * 32 + ur];
#pragma unroll
      for (int s = 0; s < 4; s++) lacc[s] = MFMA16(ones, pf[s], lacc[s]);
#pragma unroll
      for (int ct = 0; ct < 4; ct++) {
        bhalf8 va = *(const bhalf8*)&vb[(16 * ct + ln) * 64 + (sbase ^ (32 * p))];
#pragma unroll
        for (int s = 0; s < 4; s++) o[ct][s] = MFMA16(va, pf[s], o[ct][s]);
      }
    }
  }
  // emit partial (unnormalized O in bf16, l per row)
  size_t pbase = (size_t)blk * (256 * 64);
#pragma unroll
  for (int s = 0; s < 4; s++) {
    int row = 64 * w + 16 * s + ln;
#pragma unroll
    for (int ct = 0; ct < 4; ct++) {
      u32x2 pk;
      pk[0] = pk2(o[ct][s][0], o[ct][s][1]);
      pk[1] = pk2(o[ct][s][2], o[ct][s][3]);
      *(u32x2*)&Opart[pbase + (size_t)row * 64 + 16 * ct + 4 * q] = pk;
    }
    if (q == 0) Lsum[(size_t)blk * 256 + row] = lacc[s][0];
  }
}

// ---------------------------------------------------------------------------
// out (fused merge + projection + residual): max-free softmax -> merge is a
// plain sum: o = (sum_ch O_ch)/(sum_ch l_ch) + bv ; then out = x + Wo*o + bo.
// ---------------------------------------------------------------------------
extern "C" __global__ __launch_bounds__(256, 4) void out_kernel(
    const float* __restrict__ x, const u16* __restrict__ wob, const float* __restrict__ bo,
    const u16* __restrict__ Opart, const float* __restrict__ Lsum, const float* __restrict__ bv,
    float* __restrict__ out) {
  int b = blockIdx.x / NTILES, tile = blockIdx.x % NTILES;
  int t = threadIdx.x;
  int w = t >> 6, lane = t & 63, q = lane >> 4, ln = lane & 15;
  int n0w = tile * 64 + 16 * w;
  // flash partial indexing for this lane's A-row (n = n0w + ln)
  int ptile = tile >> 2;                       // 256-row flash tile
  int prow = (tile & 3) * 64 + 16 * w + ln;    // row within it
  int p0 = (b * FTILES + ptile) * NCHUNK;
  float L = 0.f;
  float acc0[8], acc1[8];
#pragma unroll
  for (int j = 0; j < 8; j++) { acc0[j] = 0.f; acc1[j] = 0.f; }
#pragma unroll
  for (int ch = 0; ch < NCHUNK; ch++) {
    L += Lsum[(size_t)(p0 + ch) * 256 + prow];
    const u16* op = Opart + ((size_t)(p0 + ch) * 256 + prow) * 64;
    u16x8 d0 = *(const u16x8*)(op + 8 * q);
    u16x8 d1 = *(const u16x8*)(op + 32 + 8 * q);
#pragma unroll
    for (int j = 0; j < 8; j++) { acc0[j] += bf2f(d0[j]); acc1[j] += bf2f(d1[j]); }
  }
  float rl = 1.0f / L;
  union { u16x8 us; bhalf8 bh; } A0, A1;
#pragma unroll
  for (int j = 0; j < 8; j++) {
    A0.us[j] = f2bf(acc0[j] * rl + bv[8 * q + j]);
    A1.us[j] = f2bf(acc1[j] * rl + bv[32 + 8 * q + j]);
  }
  bhalf8 a0 = A0.bh, a1 = A1.bh;
#pragma unroll
  for (int ct = 0; ct < 4; ct++) {
    int wrow = (16 * ct + ln) * 64;
    bhalf8 b0 = *(const bhalf8*)&wob[wrow + q * 8];
    bhalf8 b1 = *(const bhalf8*)&wob[wrow + 32 + q * 8];
    f32x4 d = {0.f, 0.f, 0.f, 0.f};
    d = MFMA16(a0, b0, d);
    d = MFMA16(a1, b1, d);
    int co = 16 * ct + ln;
    size_t base = (size_t)(b * 64 + co) * NN + n0w + 4 * q;
    f32x4 xv = *(const f32x4*)&x[base];
    float bc = bo[co];
    f32x4 ov;
#pragma unroll
    for (int r = 0; r < 4; r++) ov[r] = xv[r] + bc + d[r];
    *(f32x4*)&out[base] = ov;
  }
}

extern "C" void kernel_launch(void* const* d_in, const int* in_sizes, int n_in,
                              void* d_out, int out_size, void* d_ws, size_t ws_size,
                              hipStream_t stream) {
  (void)in_sizes; (void)n_in; (void)out_size; (void)ws_size;
  const float* x  = (const float*)d_in[0];
  const float* wq = (const float*)d_in[1];
  const float* bq = (const float*)d_in[2];
  const float* wk = (const float*)d_in[3];
  const float* bk = (const float*)d_in[4];
  const float* wv = (const float*)d_in[5];
  const float* bv = (const float*)d_in[6];
  const float* wo = (const float*)d_in[7];
  const float* bo = (const float*)d_in[8];
  float* out = (float*)d_out;
  char* ws = (char*)d_ws;
  // workspace layout (16B aligned), ~39 MB total
  float* mean = (float*)ws;                   // 256 f32
  float* rstd = (float*)(ws + 1024);          // 256 f32
  u16* wbf = (u16*)(ws + 2048);               // 16384 bf16
  u16* Qt = (u16*)(ws + 36864);               // [B][N][64] bf16  4.72MB
  u16* Kt = Qt + (size_t)BB * NN * 64;
  u16* Vt = Kt + (size_t)BB * NN * 64;
  u16* Opart = Vt + (size_t)BB * NN * 64;     // 720 * 256*64 bf16 = 23.6MB
  float* Lsum = (float*)(Opart + (size_t)BB * FTILES * NCHUNK * 256 * 64);  // 720*256 f32
  const u16* wqb = wbf;
  const u16* wkb = wbf + 4096;
  const u16* wvb = wbf + 8192;
  const u16* wob = wbf + 12288;

  prep_kernel<<<320, 256, 0, stream>>>(x, wq, wk, wv, wo, mean, rstd, wbf);
  qkv_kernel<<<BB * NTILES, 256, 0, stream>>>(x, mean, rstd, wqb, wkb, wvb, bq, bk, Qt, Kt, Vt);
  flash_kernel<<<BB * FTILES * NCHUNK, 256, 0, stream>>>(Qt, Kt, Vt, Opart, Lsum);
  out_kernel<<<BB * NTILES, 256, 0, stream>>>(x, wob, bo, Opart, Lsum, bv, out);
}

// Round 8
// 211.568 us; speedup vs baseline: 1.8000x; 1.0074x over previous
//
#include <hip/hip_runtime.h>
#include <stdint.h>

#define BB 4
#define CCH 64
#define NN 9216      // 96*96
#define NTILES 144   // NN/64  (qkv/out kernels: 64-wide n tiles)
#define FTILES 72    // NN/128 (flash: 128 Q-rows per block, 64 per wave, 2 waves)
#define NCHUNK 5     // split-K chunks, uneven (29,29,29,29,28 iters of 64 keys)

typedef unsigned short u16;
typedef __attribute__((ext_vector_type(8))) short bhalf8;   // 8 bf16 lanes of an MFMA operand
typedef __attribute__((ext_vector_type(4))) float f32x4;
typedef __attribute__((ext_vector_type(4))) u16 u16x4;
typedef __attribute__((ext_vector_type(8))) u16 u16x8;
typedef __attribute__((ext_vector_type(2))) unsigned int u32x2;

#define MFMA16(a, b, c) __builtin_amdgcn_mfma_f32_16x16x32_bf16((a), (b), (c), 0, 0, 0)

static __device__ __forceinline__ u16 f2bf(float f) {
  union { float f; unsigned u; } v; v.f = f;
  return (u16)((v.u + 0x7fffu + ((v.u >> 16) & 1u)) >> 16);  // RNE
}
static __device__ __forceinline__ float bf2f(u16 h) {
  union { unsigned u; float f; } v; v.u = ((unsigned)h) << 16; return v.f;
}
// pack two f32 -> (bf16(hi)<<16)|bf16(lo), round-half-up, 3 VALU ops total
static __device__ __forceinline__ unsigned pk2(float lo, float hi) {
  unsigned a = __float_as_uint(hi) + 0x8000u;
  unsigned b = __float_as_uint(lo) + 0x8000u;
  return __builtin_amdgcn_perm(a, b, 0x07060302u);  // bytes {a3,a2,b3,b2}
}
// async global->LDS, 16B per lane; lds dest = wave-uniform base + lane*16
static __device__ __forceinline__ void glds16(const void* g, void* l) {
  __builtin_amdgcn_global_load_lds(
      (const __attribute__((address_space(1))) unsigned int*)g,
      (__attribute__((address_space(3))) unsigned int*)l, 16, 0, 0);
}

// ---------------------------------------------------------------------------
// prep: blocks [0,256): per-(b,c) mean/rstd over 9216 spatial elems (float4).
//       blocks [256,320): convert wq,wk,wv,wo (4*4096 f32) to bf16.
// ---------------------------------------------------------------------------
extern "C" __global__ __launch_bounds__(256) void prep_kernel(
    const float* __restrict__ x,
    const float* __restrict__ wq, const float* __restrict__ wk,
    const float* __restrict__ wv, const float* __restrict__ wo,
    float* __restrict__ mean, float* __restrict__ rstd, u16* __restrict__ wbf) {
  if (blockIdx.x >= 256) {
    int i = (blockIdx.x - 256) * 256 + threadIdx.x;  // 0..16383
    const float* src = (i < 4096) ? wq : (i < 8192) ? wk : (i < 12288) ? wv : wo;
    wbf[i] = f2bf(src[i & 4095]);
    return;
  }
  int idx = blockIdx.x;
  const f32x4* p4 = (const f32x4*)(x + (size_t)idx * NN);
  float s = 0.f, ss = 0.f;
  for (int i = threadIdx.x; i < NN / 4; i += 256) {
    f32x4 v = p4[i];
#pragma unroll
    for (int j = 0; j < 4; j++) { s += v[j]; ss += v[j] * v[j]; }
  }
#pragma unroll
  for (int o = 32; o > 0; o >>= 1) { s += __shfl_xor(s, o, 64); ss += __shfl_xor(ss, o, 64); }
  __shared__ float ls[4], lss[4];
  int w = threadIdx.x >> 6;
  if ((threadIdx.x & 63) == 0) { ls[w] = s; lss[w] = ss; }
  __syncthreads();
  if (threadIdx.x == 0) {
    s = ls[0] + ls[1] + ls[2] + ls[3];
    ss = lss[0] + lss[1] + lss[2] + lss[3];
    float m = s * (1.f / NN);
    float var = ss * (1.f / NN) - m * m;
    mean[idx] = m;
    rstd[idx] = rsqrtf(var + 1e-5f);
  }
}

// ---------------------------------------------------------------------------
// qkv: fused instance-norm + 1x1 convs via MFMA.
// Qt,Kt = [B][N][64] bf16 (Q pre-scaled by 0.125*log2e), Vt = [B][64][N] bf16.
// ---------------------------------------------------------------------------
extern "C" __global__ __launch_bounds__(256, 4) void qkv_kernel(
    const float* __restrict__ x,
    const float* __restrict__ mean, const float* __restrict__ rstd,
    const u16* __restrict__ wqb, const u16* __restrict__ wkb, const u16* __restrict__ wvb,
    const float* __restrict__ bq, const float* __restrict__ bk,
    u16* __restrict__ Qt, u16* __restrict__ Kt, u16* __restrict__ Vt) {
  __shared__ u16 hbuf[64 * 72];  // [n_local][c], padded rows
  int b = blockIdx.x / NTILES, tile = blockIdx.x % NTILES;
  int n0 = tile * 64;
  int t = threadIdx.x;
  int w = t >> 6, lane = t & 63, q = lane >> 4, ln = lane & 15;
  const float QSCALE = 0.125f * 1.44269504088896340736f;  // C^-0.5 * log2(e)
  const float* mb = mean + b * 64;
  const float* rb_ = rstd + b * 64;
  int nloc = lane;
#pragma unroll
  for (int rep = 0; rep < 4; rep++) {
    int c0 = 16 * w + 4 * rep;  // wave-uniform
    float h0 = (x[(size_t)(b * 64 + c0 + 0) * NN + n0 + nloc] - mb[c0 + 0]) * rb_[c0 + 0];
    float h1 = (x[(size_t)(b * 64 + c0 + 1) * NN + n0 + nloc] - mb[c0 + 1]) * rb_[c0 + 1];
    float h2 = (x[(size_t)(b * 64 + c0 + 2) * NN + n0 + nloc] - mb[c0 + 2]) * rb_[c0 + 2];
    float h3 = (x[(size_t)(b * 64 + c0 + 3) * NN + n0 + nloc] - mb[c0 + 3]) * rb_[c0 + 3];
    u32x2 hp;
    hp[0] = pk2(h0, h1);
    hp[1] = pk2(h2, h3);
    *(u32x2*)&hbuf[nloc * 72 + c0] = hp;
  }
  __syncthreads();
  int hrow = (16 * w + ln) * 72;
  bhalf8 hb0 = *(const bhalf8*)&hbuf[hrow + q * 8];
  bhalf8 hb1 = *(const bhalf8*)&hbuf[hrow + 32 + q * 8];
  size_t nrow = (size_t)(b * NN + n0 + 16 * w + ln) * 64;
  // ---- Q (transposed orientation: reg quad = 4 consecutive channels) ----
#pragma unroll
  for (int ct = 0; ct < 4; ct++) {
    int wrow = (16 * ct + ln) * 64;
    bhalf8 a0 = *(const bhalf8*)&wqb[wrow + q * 8];
    bhalf8 a1 = *(const bhalf8*)&wqb[wrow + 32 + q * 8];
    f32x4 d = {0.f, 0.f, 0.f, 0.f};
    d = MFMA16(a0, hb0, d);
    d = MFMA16(a1, hb1, d);
    f32x4 b4 = *(const f32x4*)&bq[16 * ct + 4 * q];
    u16x4 pk;
#pragma unroll
    for (int r = 0; r < 4; r++) pk[r] = f2bf((d[r] + b4[r]) * QSCALE);
    *(u16x4*)&Qt[nrow + 16 * ct + 4 * q] = pk;
  }
  // ---- K ----
#pragma unroll
  for (int ct = 0; ct < 4; ct++) {
    int wrow = (16 * ct + ln) * 64;
    bhalf8 a0 = *(const bhalf8*)&wkb[wrow + q * 8];
    bhalf8 a1 = *(const bhalf8*)&wkb[wrow + 32 + q * 8];
    f32x4 d = {0.f, 0.f, 0.f, 0.f};
    d = MFMA16(a0, hb0, d);
    d = MFMA16(a1, hb1, d);
    f32x4 b4 = *(const f32x4*)&bk[16 * ct + 4 * q];
    u16x4 pk;
#pragma unroll
    for (int r = 0; r < 4; r++) pk[r] = f2bf(d[r] + b4[r]);
    *(u16x4*)&Kt[nrow + 16 * ct + 4 * q] = pk;
  }
  // ---- V (normal orientation; bv folded into epilogue) ----
#pragma unroll
  for (int ct = 0; ct < 4; ct++) {
    int wrow = (16 * ct + ln) * 64;
    bhalf8 b0 = *(const bhalf8*)&wvb[wrow + q * 8];
    bhalf8 b1 = *(const bhalf8*)&wvb[wrow + 32 + q * 8];
    f32x4 d = {0.f, 0.f, 0.f, 0.f};
    d = MFMA16(hb0, b0, d);
    d = MFMA16(hb1, b1, d);
    u16x4 pk;
#pragma unroll
    for (int r = 0; r < 4; r++) pk[r] = f2bf(d[r]);
    *(u16x4*)&Vt[(size_t)(b * 64 + 16 * ct + ln) * NN + n0 + 16 * w + 4 * q] = pk;
  }
}

// ---------------------------------------------------------------------------
// flash: split-K attention, max-free softmax, 64 Q-rows/wave, 128-THREAD
// BLOCKS (2 waves). Occupancy was grid-limited at 24% (R7, 720 blocks);
// halving the block doubles the grid to 1440 at constant total work and
// LDS/block = 8K + 8V + 2x4P = 24KB -> 6 blocks/CU, ~11 waves/CU resident.
// Single K/V buffer (R6: double-buffering measured neutral).
// ---------------------------------------------------------------------------
extern "C" __global__ __launch_bounds__(128, 3) void flash_kernel(
    const u16* __restrict__ Qt, const u16* __restrict__ Kt, const u16* __restrict__ Vt,
    u16* __restrict__ Opart, float* __restrict__ Lsum) {
  __shared__ u16 kbuf[64 * 64];        // [m_local][c], 16B units swizzled by (row&7)
  __shared__ u16 vbuf[64 * 64];        // [c][m_local], 16B units swizzled by (row&7)
  __shared__ u16 pbuf[2][64 * 32];     // per-wave [n_local(64)][32 keys], 4-unit XOR swizzle
  int blk = blockIdx.x;
  int b = blk / (FTILES * NCHUNK);
  int rem = blk % (FTILES * NCHUNK);
  int tile = rem / NCHUNK, chunk = rem % NCHUNK;
  int it0 = chunk * 28 + (chunk < 4 ? chunk : 4);   // 0,29,58,87,116
  int nit = 28 + (chunk < 4 ? 1 : 0);               // 29,29,29,29,28
  int m_start = it0 * 64;
  int t = threadIdx.x;
  int w = t >> 6, lane = t & 63, q = lane >> 4, ln = lane & 15;
  int n0w = tile * 128 + 64 * w;
  // Q fragments for 4 sets of 16 rows each
  bhalf8 qf0[4], qf1[4];
#pragma unroll
  for (int s = 0; s < 4; s++) {
    const u16* qp = Qt + (size_t)(b * NN + n0w + 16 * s + ln) * 64 + q * 8;
    qf0[s] = *(const bhalf8*)qp;
    qf1[s] = *(const bhalf8*)(qp + 32);
  }
  const short ONE = 0x3F80;            // bf16 1.0
  const bhalf8 ones = {ONE, ONE, ONE, ONE, ONE, ONE, ONE, ONE};
  f32x4 o[4][4];                       // [ct][set]
  f32x4 lacc[4];
#pragma unroll
  for (int ct = 0; ct < 4; ct++) {
    lacc[ct] = (f32x4){0.f, 0.f, 0.f, 0.f};
#pragma unroll
    for (int s = 0; s < 4; s++) o[ct][s] = (f32x4){0.f, 0.f, 0.f, 0.f};
  }
  u16* pw = pbuf[w];
  // staging: wave w fills LDS rows [32w,32w+32); lane covers rows 32w+(lane>>3)+{0,8,16,24}
  int r0 = 32 * w + (lane >> 3);
  int usw = (lane & 7) ^ (r0 & 7);     // swizzled global 16B-chunk index ((r0+8k)&7 == r0&7)
  const u16* kgp = Kt + ((size_t)b * NN + m_start + r0) * 64 + usw * 8;
  const u16* vgp = Vt + (size_t)(b * 64 + r0) * NN + m_start + usw * 8;
  u16* klds = &kbuf[w * 2048];
  u16* vlds = &vbuf[w * 2048];
  int sbase = (q ^ (ln & 15 & 7)) * 8; // = (q ^ (ln&7))*8, swizzled K/V fragment offset

  for (int i = 0; i < nit; i++) {
    __syncthreads();                   // all waves done reading previous tile
#pragma unroll
    for (int k = 0; k < 4; k++) {
      glds16(kgp + k * 512, klds + k * 512);           // K rows r0+8k
      glds16(vgp + (size_t)(8 * k) * NN, vlds + k * 512);  // V rows r0+8k
    }
    kgp += 4096;                       // 64 keys * 64 ch
    vgp += 64;                         // 64 keys along N
    __syncthreads();                   // staged data visible
#pragma unroll
    for (int p = 0; p < 2; p++) {      // two 32-key phases
#pragma unroll
      for (int lm = 0; lm < 2; lm++) { // 16 keys each
        int krow = (16 * (2 * p + lm) + ln) * 64;
        bhalf8 ka0 = *(const bhalf8*)&kbuf[krow + sbase];
        bhalf8 ka1 = *(const bhalf8*)&kbuf[krow + (sbase ^ 32)];
        int uw = (((2 * lm + (q >> 1)) ^ ((ln >> 1) & 3)) << 3) + ((q & 1) << 2);
#pragma unroll
        for (int s = 0; s < 4; s++) {
          f32x4 acc = {0.f, 0.f, 0.f, 0.f};
          acc = MFMA16(ka0, qf0[s], acc);
          acc = MFMA16(ka1, qf1[s], acc);
          f32x4 pv;
#pragma unroll
          for (int r = 0; r < 4; r++) pv[r] = __builtin_amdgcn_exp2f(acc[r]);
          u32x2 pk;
          pk[0] = pk2(pv[0], pv[1]);
          pk[1] = pk2(pv[2], pv[3]);
          *(u32x2*)&pw[(16 * s + ln) * 32 + uw] = pk;
        }
      }
      // PV for this 32-key phase: O^T += V^T * P^T ; l via ones-A MFMA
      int ur = ((q ^ ((ln >> 1) & 3)) << 3);
      bhalf8 pf[4];
#pragma unroll
      for (int s = 0; s < 4; s++) pf[s] = *(const bhalf8*)&pw[(16 * s + ln) * 32 + ur];
#pragma unroll
      for (int s = 0; s < 4; s++) lacc[s] = MFMA16(ones, pf[s], lacc[s]);
#pragma unroll
      for (int ct = 0; ct < 4; ct++) {
        bhalf8 va = *(const bhalf8*)&vbuf[(16 * ct + ln) * 64 + (sbase ^ (32 * p))];
#pragma unroll
        for (int s = 0; s < 4; s++) o[ct][s] = MFMA16(va, pf[s], o[ct][s]);
      }
    }
  }
  // emit partial (unnormalized O in bf16, l per row)
  size_t pbase = (size_t)blk * (128 * 64);
#pragma unroll
  for (int s = 0; s < 4; s++) {
    int row = 64 * w + 16 * s + ln;
#pragma unroll
    for (int ct = 0; ct < 4; ct++) {
      u32x2 pk;
      pk[0] = pk2(o[ct][s][0], o[ct][s][1]);
      pk[1] = pk2(o[ct][s][2], o[ct][s][3]);
      *(u32x2*)&Opart[pbase + (size_t)row * 64 + 16 * ct + 4 * q] = pk;
    }
    if (q == 0) Lsum[(size_t)blk * 128 + row] = lacc[s][0];
  }
}

// ---------------------------------------------------------------------------
// out (fused merge + projection + residual): max-free softmax -> merge is a
// plain sum: o = (sum_ch O_ch)/(sum_ch l_ch) + bv ; then out = x + Wo*o + bo.
// ---------------------------------------------------------------------------
extern "C" __global__ __launch_bounds__(256, 4) void out_kernel(
    const float* __restrict__ x, const u16* __restrict__ wob, const float* __restrict__ bo,
    const u16* __restrict__ Opart, const float* __restrict__ Lsum, const float* __restrict__ bv,
    float* __restrict__ out) {
  int b = blockIdx.x / NTILES, tile = blockIdx.x % NTILES;
  int t = threadIdx.x;
  int w = t >> 6, lane = t & 63, q = lane >> 4, ln = lane & 15;
  int n0w = tile * 64 + 16 * w;
  // flash partial indexing for this lane's A-row (n = n0w + ln)
  int ptile = tile >> 1;                       // 128-row flash tile
  int prow = (tile & 1) * 64 + 16 * w + ln;    // row within it
  int p0 = (b * FTILES + ptile) * NCHUNK;
  float L = 0.f;
  float acc0[8], acc1[8];
#pragma unroll
  for (int j = 0; j < 8; j++) { acc0[j] = 0.f; acc1[j] = 0.f; }
#pragma unroll
  for (int ch = 0; ch < NCHUNK; ch++) {
    L += Lsum[(size_t)(p0 + ch) * 128 + prow];
    const u16* op = Opart + ((size_t)(p0 + ch) * 128 + prow) * 64;
    u16x8 d0 = *(const u16x8*)(op + 8 * q);
    u16x8 d1 = *(const u16x8*)(op + 32 + 8 * q);
#pragma unroll
    for (int j = 0; j < 8; j++) { acc0[j] += bf2f(d0[j]); acc1[j] += bf2f(d1[j]); }
  }
  float rl = 1.0f / L;
  union { u16x8 us; bhalf8 bh; } A0, A1;
#pragma unroll
  for (int j = 0; j < 8; j++) {
    A0.us[j] = f2bf(acc0[j] * rl + bv[8 * q + j]);
    A1.us[j] = f2bf(acc1[j] * rl + bv[32 + 8 * q + j]);
  }
  bhalf8 a0 = A0.bh, a1 = A1.bh;
#pragma unroll
  for (int ct = 0; ct < 4; ct++) {
    int wrow = (16 * ct + ln) * 64;
    bhalf8 b0 = *(const bhalf8*)&wob[wrow + q * 8];
    bhalf8 b1 = *(const bhalf8*)&wob[wrow + 32 + q * 8];
    f32x4 d = {0.f, 0.f, 0.f, 0.f};
    d = MFMA16(a0, b0, d);
    d = MFMA16(a1, b1, d);
    int co = 16 * ct + ln;
    size_t base = (size_t)(b * 64 + co) * NN + n0w + 4 * q;
    f32x4 xv = *(const f32x4*)&x[base];
    float bc = bo[co];
    f32x4 ov;
#pragma unroll
    for (int r = 0; r < 4; r++) ov[r] = xv[r] + bc + d[r];
    *(f32x4*)&out[base] = ov;
  }
}

extern "C" void kernel_launch(void* const* d_in, const int* in_sizes, int n_in,
                              void* d_out, int out_size, void* d_ws, size_t ws_size,
                              hipStream_t stream) {
  (void)in_sizes; (void)n_in; (void)out_size; (void)ws_size;
  const float* x  = (const float*)d_in[0];
  const float* wq = (const float*)d_in[1];
  const float* bq = (const float*)d_in[2];
  const float* wk = (const float*)d_in[3];
  const float* bk = (const float*)d_in[4];
  const float* wv = (const float*)d_in[5];
  const float* bv = (const float*)d_in[6];
  const float* wo = (const float*)d_in[7];
  const float* bo = (const float*)d_in[8];
  float* out = (float*)d_out;
  char* ws = (char*)d_ws;
  // workspace layout (16B aligned), ~39 MB total
  float* mean = (float*)ws;                   // 256 f32
  float* rstd = (float*)(ws + 1024);          // 256 f32
  u16* wbf = (u16*)(ws + 2048);               // 16384 bf16
  u16* Qt = (u16*)(ws + 36864);               // [B][N][64] bf16  4.72MB
  u16* Kt = Qt + (size_t)BB * NN * 64;
  u16* Vt = Kt + (size_t)BB * NN * 64;
  u16* Opart = Vt + (size_t)BB * NN * 64;     // 1440 * 128*64 bf16 = 23.6MB
  float* Lsum = (float*)(Opart + (size_t)BB * FTILES * NCHUNK * 128 * 64);  // 1440*128 f32
  const u16* wqb = wbf;
  const u16* wkb = wbf + 4096;
  const u16* wvb = wbf + 8192;
  const u16* wob = wbf + 12288;

  prep_kernel<<<320, 256, 0, stream>>>(x, wq, wk, wv, wo, mean, rstd, wbf);
  qkv_kernel<<<BB * NTILES, 256, 0, stream>>>(x, mean, rstd, wqb, wkb, wvb, bq, bk, Qt, Kt, Vt);
  flash_kernel<<<BB * FTILES * NCHUNK, 128, 0, stream>>>(Qt, Kt, Vt, Opart, Lsum);
  out_kernel<<<BB * NTILES, 256, 0, stream>>>(x, wob, bo, Opart, Lsum, bv, out);
}

// Round 9
// 202.630 us; speedup vs baseline: 1.8794x; 1.0441x over previous
//
#include <hip/hip_runtime.h>
#include <stdint.h>

#define BB 4
#define CCH 64
#define NN 9216      // 96*96
#define NTILES 144   // NN/64  (qkv/out kernels: 64-wide n tiles)
#define FTILES 36    // NN/256 (flash: 256 Q-rows per block, 64 per wave)
#define NCHUNK 5     // split-K chunks, uneven (29,29,29,29,28 iters of 64 keys)

typedef unsigned short u16;
typedef __attribute__((ext_vector_type(8))) short bhalf8;   // 8 bf16 lanes of an MFMA operand
typedef __attribute__((ext_vector_type(4))) float f32x4;
typedef __attribute__((ext_vector_type(4))) u16 u16x4;
typedef __attribute__((ext_vector_type(8))) u16 u16x8;
typedef __attribute__((ext_vector_type(2))) unsigned int u32x2;

#define MFMA16(a, b, c) __builtin_amdgcn_mfma_f32_16x16x32_bf16((a), (b), (c), 0, 0, 0)

static __device__ __forceinline__ u16 f2bf(float f) {
  union { float f; unsigned u; } v; v.f = f;
  return (u16)((v.u + 0x7fffu + ((v.u >> 16) & 1u)) >> 16);  // RNE
}
static __device__ __forceinline__ float bf2f(u16 h) {
  union { unsigned u; float f; } v; v.u = ((unsigned)h) << 16; return v.f;
}
// pack two f32 -> (bf16(hi)<<16)|bf16(lo), round-half-up, 3 VALU ops total
static __device__ __forceinline__ unsigned pk2(float lo, float hi) {
  unsigned a = __float_as_uint(hi) + 0x8000u;
  unsigned b = __float_as_uint(lo) + 0x8000u;
  return __builtin_amdgcn_perm(a, b, 0x07060302u);  // bytes {a3,a2,b3,b2}
}
// async global->LDS, 16B per lane; lds dest = wave-uniform base + lane*16
static __device__ __forceinline__ void glds16(const void* g, void* l) {
  __builtin_amdgcn_global_load_lds(
      (const __attribute__((address_space(1))) unsigned int*)g,
      (__attribute__((address_space(3))) unsigned int*)l, 16, 0, 0);
}

// ---------------------------------------------------------------------------
// prep: blocks [0,256): per-(b,c) mean/rstd over 9216 spatial elems (float4).
//       blocks [256,320): convert wq,wk,wv,wo (4*4096 f32) to bf16.
// ---------------------------------------------------------------------------
extern "C" __global__ __launch_bounds__(256) void prep_kernel(
    const float* __restrict__ x,
    const float* __restrict__ wq, const float* __restrict__ wk,
    const float* __restrict__ wv, const float* __restrict__ wo,
    float* __restrict__ mean, float* __restrict__ rstd, u16* __restrict__ wbf) {
  if (blockIdx.x >= 256) {
    int i = (blockIdx.x - 256) * 256 + threadIdx.x;  // 0..16383
    const float* src = (i < 4096) ? wq : (i < 8192) ? wk : (i < 12288) ? wv : wo;
    wbf[i] = f2bf(src[i & 4095]);
    return;
  }
  int idx = blockIdx.x;
  const f32x4* p4 = (const f32x4*)(x + (size_t)idx * NN);
  float s = 0.f, ss = 0.f;
  for (int i = threadIdx.x; i < NN / 4; i += 256) {
    f32x4 v = p4[i];
#pragma unroll
    for (int j = 0; j < 4; j++) { s += v[j]; ss += v[j] * v[j]; }
  }
#pragma unroll
  for (int o = 32; o > 0; o >>= 1) { s += __shfl_xor(s, o, 64); ss += __shfl_xor(ss, o, 64); }
  __shared__ float ls[4], lss[4];
  int w = threadIdx.x >> 6;
  if ((threadIdx.x & 63) == 0) { ls[w] = s; lss[w] = ss; }
  __syncthreads();
  if (threadIdx.x == 0) {
    s = ls[0] + ls[1] + ls[2] + ls[3];
    ss = lss[0] + lss[1] + lss[2] + lss[3];
    float m = s * (1.f / NN);
    float var = ss * (1.f / NN) - m * m;
    mean[idx] = m;
    rstd[idx] = rsqrtf(var + 1e-5f);
  }
}

// ---------------------------------------------------------------------------
// qkv: fused instance-norm + 1x1 convs via MFMA.
// Qt,Kt = [B][N][64] bf16 (Q pre-scaled by 0.125*log2e), Vt = [B][64][N] bf16.
// NEW: MFMA result quads route through an LDS transpose tile so all global
// stores are fully coalesced (16B/lane contiguous) instead of the C-layout
// scatter (8B per lane at 128B..18KB strides -> 16 line-touches per instr).
// ---------------------------------------------------------------------------
extern "C" __global__ __launch_bounds__(256, 4) void qkv_kernel(
    const float* __restrict__ x,
    const float* __restrict__ mean, const float* __restrict__ rstd,
    const u16* __restrict__ wqb, const u16* __restrict__ wkb, const u16* __restrict__ wvb,
    const float* __restrict__ bq, const float* __restrict__ bk,
    u16* __restrict__ Qt, u16* __restrict__ Kt, u16* __restrict__ Vt) {
  __shared__ u16 smem[64 * 72];  // staging hbuf (stride 72), then transpose tile (stride 68)
  int b = blockIdx.x / NTILES, tile = blockIdx.x % NTILES;
  int n0 = tile * 64;
  int t = threadIdx.x;
  int w = t >> 6, lane = t & 63, q = lane >> 4, ln = lane & 15;
  const float QSCALE = 0.125f * 1.44269504088896340736f;  // C^-0.5 * log2(e)
  const float* mb = mean + b * 64;
  const float* rb_ = rstd + b * 64;
  int nloc = lane;
#pragma unroll
  for (int rep = 0; rep < 4; rep++) {
    int c0 = 16 * w + 4 * rep;  // wave-uniform
    float h0 = (x[(size_t)(b * 64 + c0 + 0) * NN + n0 + nloc] - mb[c0 + 0]) * rb_[c0 + 0];
    float h1 = (x[(size_t)(b * 64 + c0 + 1) * NN + n0 + nloc] - mb[c0 + 1]) * rb_[c0 + 1];
    float h2 = (x[(size_t)(b * 64 + c0 + 2) * NN + n0 + nloc] - mb[c0 + 2]) * rb_[c0 + 2];
    float h3 = (x[(size_t)(b * 64 + c0 + 3) * NN + n0 + nloc] - mb[c0 + 3]) * rb_[c0 + 3];
    u32x2 hp;
    hp[0] = pk2(h0, h1);
    hp[1] = pk2(h2, h3);
    *(u32x2*)&smem[nloc * 72 + c0] = hp;
  }
  __syncthreads();
  int hrow = (16 * w + ln) * 72;
  bhalf8 hb0 = *(const bhalf8*)&smem[hrow + q * 8];
  bhalf8 hb1 = *(const bhalf8*)&smem[hrow + 32 + q * 8];
  __syncthreads();  // all waves have h-frags in registers; smem is now reusable

  int row_st = t >> 3, ch_st = (t & 7) * 8;  // coalesced-store pass indexing
  // ---- Q (transposed orientation: quad = 4 consecutive channels) ----
#pragma unroll
  for (int ct = 0; ct < 4; ct++) {
    int wrow = (16 * ct + ln) * 64;
    bhalf8 a0 = *(const bhalf8*)&wqb[wrow + q * 8];
    bhalf8 a1 = *(const bhalf8*)&wqb[wrow + 32 + q * 8];
    f32x4 d = {0.f, 0.f, 0.f, 0.f};
    d = MFMA16(a0, hb0, d);
    d = MFMA16(a1, hb1, d);
    f32x4 b4 = *(const f32x4*)&bq[16 * ct + 4 * q];
    u32x2 pk;
    pk[0] = pk2((d[0] + b4[0]) * QSCALE, (d[1] + b4[1]) * QSCALE);
    pk[1] = pk2((d[2] + b4[2]) * QSCALE, (d[3] + b4[3]) * QSCALE);
    *(u32x2*)&smem[(16 * w + ln) * 68 + 16 * ct + 4 * q] = pk;  // [n][c]
  }
  __syncthreads();
#pragma unroll
  for (int pass = 0; pass < 2; pass++) {
    int n = 32 * pass + row_st;
    *(u16x8*)&Qt[(size_t)(b * NN + n0 + n) * 64 + ch_st] = *(const u16x8*)&smem[n * 68 + ch_st];
  }
  __syncthreads();
  // ---- K ----
#pragma unroll
  for (int ct = 0; ct < 4; ct++) {
    int wrow = (16 * ct + ln) * 64;
    bhalf8 a0 = *(const bhalf8*)&wkb[wrow + q * 8];
    bhalf8 a1 = *(const bhalf8*)&wkb[wrow + 32 + q * 8];
    f32x4 d = {0.f, 0.f, 0.f, 0.f};
    d = MFMA16(a0, hb0, d);
    d = MFMA16(a1, hb1, d);
    f32x4 b4 = *(const f32x4*)&bk[16 * ct + 4 * q];
    u32x2 pk;
    pk[0] = pk2(d[0] + b4[0], d[1] + b4[1]);
    pk[1] = pk2(d[2] + b4[2], d[3] + b4[3]);
    *(u32x2*)&smem[(16 * w + ln) * 68 + 16 * ct + 4 * q] = pk;  // [n][c]
  }
  __syncthreads();
#pragma unroll
  for (int pass = 0; pass < 2; pass++) {
    int n = 32 * pass + row_st;
    *(u16x8*)&Kt[(size_t)(b * NN + n0 + n) * 64 + ch_st] = *(const u16x8*)&smem[n * 68 + ch_st];
  }
  __syncthreads();
  // ---- V (normal orientation: quad = 4 consecutive n; bv folded into out) ----
#pragma unroll
  for (int ct = 0; ct < 4; ct++) {
    int wrow = (16 * ct + ln) * 64;
    bhalf8 b0 = *(const bhalf8*)&wvb[wrow + q * 8];
    bhalf8 b1 = *(const bhalf8*)&wvb[wrow + 32 + q * 8];
    f32x4 d = {0.f, 0.f, 0.f, 0.f};
    d = MFMA16(hb0, b0, d);
    d = MFMA16(hb1, b1, d);
    u32x2 pk;
    pk[0] = pk2(d[0], d[1]);
    pk[1] = pk2(d[2], d[3]);
    *(u32x2*)&smem[(16 * ct + ln) * 68 + 16 * w + 4 * q] = pk;  // [c][n]
  }
  __syncthreads();
#pragma unroll
  for (int pass = 0; pass < 2; pass++) {
    int c = 32 * pass + row_st;
    *(u16x8*)&Vt[(size_t)(b * 64 + c) * NN + n0 + ch_st] = *(const u16x8*)&smem[c * 68 + ch_st];
  }
}

// ---------------------------------------------------------------------------
// flash: split-K attention, max-free softmax, 64 Q-rows per wave (R7 config —
// best measured; R8's 2-wave blocks were neutral-negative).
// Block = 4 waves x 64 rows = 256 Q-rows; one of 5 uneven key-chunks.
// LDS = 2x8K + 2x8V + 16P = 48KB -> 3 blocks/CU.
// ---------------------------------------------------------------------------
extern "C" __global__ __launch_bounds__(256, 3) void flash_kernel(
    const u16* __restrict__ Qt, const u16* __restrict__ Kt, const u16* __restrict__ Vt,
    u16* __restrict__ Opart, float* __restrict__ Lsum) {
  __shared__ u16 kbuf[2][64 * 64];     // [m_local][c], 16B units swizzled by (row&7)
  __shared__ u16 vbuf[2][64 * 64];     // [c][m_local], 16B units swizzled by (row&7)
  __shared__ u16 pbuf[4][64 * 32];     // per-wave [n_local(64)][32 keys], 4-unit XOR swizzle
  int blk = blockIdx.x;
  int b = blk / (FTILES * NCHUNK);
  int rem = blk % (FTILES * NCHUNK);
  int tile = rem / NCHUNK, chunk = rem % NCHUNK;
  int it0 = chunk * 28 + (chunk < 4 ? chunk : 4);   // 0,29,58,87,116
  int nit = 28 + (chunk < 4 ? 1 : 0);               // 29,29,29,29,28
  int m_start = it0 * 64;
  int t = threadIdx.x;
  int w = t >> 6, lane = t & 63, q = lane >> 4, ln = lane & 15;
  int n0w = tile * 256 + 64 * w;
  // Q fragments for 4 sets of 16 rows each
  bhalf8 qf0[4], qf1[4];
#pragma unroll
  for (int s = 0; s < 4; s++) {
    const u16* qp = Qt + (size_t)(b * NN + n0w + 16 * s + ln) * 64 + q * 8;
    qf0[s] = *(const bhalf8*)qp;
    qf1[s] = *(const bhalf8*)(qp + 32);
  }
  const short ONE = 0x3F80;            // bf16 1.0
  const bhalf8 ones = {ONE, ONE, ONE, ONE, ONE, ONE, ONE, ONE};
  f32x4 o[4][4];                       // [ct][set]
  f32x4 lacc[4];
#pragma unroll
  for (int ct = 0; ct < 4; ct++) {
    lacc[ct] = (f32x4){0.f, 0.f, 0.f, 0.f};
#pragma unroll
    for (int s = 0; s < 4; s++) o[ct][s] = (f32x4){0.f, 0.f, 0.f, 0.f};
  }
  u16* pw = pbuf[w];
  // staging: wave w fills LDS rows [16w,16w+16); lane covers (row 16w+(lane>>3), unit lane&7)
  int row_s = 16 * w + (lane >> 3);
  int usw = (lane & 7) ^ (row_s & 7);  // swizzled global 16B-chunk index
  const u16* kgp = Kt + ((size_t)b * NN + m_start + row_s) * 64 + usw * 8;
  const u16* vgp = Vt + (size_t)(b * 64 + row_s) * NN + m_start + usw * 8;
  int sbase = (q ^ (ln & 7)) * 8;      // swizzled chunk offset for K/V fragment reads

  // prologue: DMA tile 0 -> buffer 0
  {
    u16* kl = &kbuf[0][w * 1024];
    u16* vl = &vbuf[0][w * 1024];
    glds16(kgp, kl); glds16(kgp + 512, kl + 512);
    glds16(vgp, vl); glds16(vgp + (size_t)8 * NN, vl + 512);
    kgp += 4096; vgp += 64;
  }

  for (int i = 0; i < nit; i++) {
    __syncthreads();
    if (i + 1 < nit) {                 // prefetch tile i+1 into the other buffer
      u16* kl = &kbuf[(i + 1) & 1][w * 1024];
      u16* vl = &vbuf[(i + 1) & 1][w * 1024];
      glds16(kgp, kl); glds16(kgp + 512, kl + 512);
      glds16(vgp, vl); glds16(vgp + (size_t)8 * NN, vl + 512);
      kgp += 4096; vgp += 64;
    }
    const u16* kb = kbuf[i & 1];
    const u16* vb = vbuf[i & 1];
#pragma unroll
    for (int p = 0; p < 2; p++) {      // two 32-key phases
#pragma unroll
      for (int lm = 0; lm < 2; lm++) { // 16 keys each
        int krow = (16 * (2 * p + lm) + ln) * 64;
        bhalf8 ka0 = *(const bhalf8*)&kb[krow + sbase];
        bhalf8 ka1 = *(const bhalf8*)&kb[krow + (sbase ^ 32)];
        int uw = (((2 * lm + (q >> 1)) ^ ((ln >> 1) & 3)) << 3) + ((q & 1) << 2);
#pragma unroll
        for (int s = 0; s < 4; s++) {
          f32x4 acc = {0.f, 0.f, 0.f, 0.f};
          acc = MFMA16(ka0, qf0[s], acc);
          acc = MFMA16(ka1, qf1[s], acc);
          f32x4 pv;
#pragma unroll
          for (int r = 0; r < 4; r++) pv[r] = __builtin_amdgcn_exp2f(acc[r]);
          u32x2 pk;
          pk[0] = pk2(pv[0], pv[1]);
          pk[1] = pk2(pv[2], pv[3]);
          *(u32x2*)&pw[(16 * s + ln) * 32 + uw] = pk;
        }
      }
      // PV for this 32-key phase: O^T += V^T * P^T ; l via ones-A MFMA
      int ur = ((q ^ ((ln >> 1) & 3)) << 3);
      bhalf8 pf[4];
#pragma unroll
      for (int s = 0; s < 4; s++) pf[s] = *(const bhalf8*)&pw[(16 * s + ln) * 32 + ur];
#pragma unroll
      for (int s = 0; s < 4; s++) lacc[s] = MFMA16(ones, pf[s], lacc[s]);
#pragma unroll
      for (int ct = 0; ct < 4; ct++) {
        bhalf8 va = *(const bhalf8*)&vb[(16 * ct + ln) * 64 + (sbase ^ (32 * p))];
#pragma unroll
        for (int s = 0; s < 4; s++) o[ct][s] = MFMA16(va, pf[s], o[ct][s]);
      }
    }
  }
  // emit partial (unnormalized O in bf16, l per row)
  size_t pbase = (size_t)blk * (256 * 64);
#pragma unroll
  for (int s = 0; s < 4; s++) {
    int row = 64 * w + 16 * s + ln;
#pragma unroll
    for (int ct = 0; ct < 4; ct++) {
      u32x2 pk;
      pk[0] = pk2(o[ct][s][0], o[ct][s][1]);
      pk[1] = pk2(o[ct][s][2], o[ct][s][3]);
      *(u32x2*)&Opart[pbase + (size_t)row * 64 + 16 * ct + 4 * q] = pk;
    }
    if (q == 0) Lsum[(size_t)blk * 256 + row] = lacc[s][0];
  }
}

// ---------------------------------------------------------------------------
// out (fused merge + projection + residual): o = (sum_ch O_ch)/(sum_ch l_ch)
// + bv ; out = x + Wo*o + bo. NEW: result routes through an LDS f32 tile so
// the x-read and out-store happen at fully coalesced addresses (the C-layout
// scatter was 16B/lane at 18KB stride -> 16 line-touches per instr).
// ---------------------------------------------------------------------------
extern "C" __global__ __launch_bounds__(256, 4) void out_kernel(
    const float* __restrict__ x, const u16* __restrict__ wob, const float* __restrict__ bo,
    const u16* __restrict__ Opart, const float* __restrict__ Lsum, const float* __restrict__ bv,
    float* __restrict__ out) {
  __shared__ float fbuf[64 * 68];  // [c][n] f32, padded stride
  int b = blockIdx.x / NTILES, tile = blockIdx.x % NTILES;
  int t = threadIdx.x;
  int w = t >> 6, lane = t & 63, q = lane >> 4, ln = lane & 15;
  int n0 = tile * 64;
  // flash partial indexing for this lane's A-row (n = n0 + 16w + ln)
  int ptile = tile >> 2;                       // 256-row flash tile
  int prow = (tile & 3) * 64 + 16 * w + ln;    // row within it
  int p0 = (b * FTILES + ptile) * NCHUNK;
  float L = 0.f;
  float acc0[8], acc1[8];
#pragma unroll
  for (int j = 0; j < 8; j++) { acc0[j] = 0.f; acc1[j] = 0.f; }
#pragma unroll
  for (int ch = 0; ch < NCHUNK; ch++) {
    L += Lsum[(size_t)(p0 + ch) * 256 + prow];
    const u16* op = Opart + ((size_t)(p0 + ch) * 256 + prow) * 64;
    u16x8 d0 = *(const u16x8*)(op + 8 * q);
    u16x8 d1 = *(const u16x8*)(op + 32 + 8 * q);
#pragma unroll
    for (int j = 0; j < 8; j++) { acc0[j] += bf2f(d0[j]); acc1[j] += bf2f(d1[j]); }
  }
  float rl = 1.0f / L;
  union { u16x8 us; bhalf8 bh; } A0, A1;
#pragma unroll
  for (int j = 0; j < 8; j++) {
    A0.us[j] = f2bf(acc0[j] * rl + bv[8 * q + j]);
    A1.us[j] = f2bf(acc1[j] * rl + bv[32 + 8 * q + j]);
  }
  bhalf8 a0 = A0.bh, a1 = A1.bh;
#pragma unroll
  for (int ct = 0; ct < 4; ct++) {
    int wrow = (16 * ct + ln) * 64;
    bhalf8 b0 = *(const bhalf8*)&wob[wrow + q * 8];
    bhalf8 b1 = *(const bhalf8*)&wob[wrow + 32 + q * 8];
    f32x4 d = {0.f, 0.f, 0.f, 0.f};
    d = MFMA16(a0, b0, d);
    d = MFMA16(a1, b1, d);
    // lane holds quad of 4 consecutive n (16w+4q+r) for channel co=16ct+ln
    *(f32x4*)&fbuf[(16 * ct + ln) * 68 + 16 * w + 4 * q] = d;
  }
  __syncthreads();
  // coalesced epilogue: residual + bias + store, 16B/lane contiguous
#pragma unroll
  for (int pass = 0; pass < 4; pass++) {
    int co = 16 * pass + (t >> 4);
    int chk = t & 15;
    f32x4 v = *(const f32x4*)&fbuf[co * 68 + chk * 4];
    size_t base = (size_t)(b * 64 + co) * NN + n0 + chk * 4;
    f32x4 xv = *(const f32x4*)&x[base];
    float bc = bo[co];
    f32x4 ov;
#pragma unroll
    for (int r = 0; r < 4; r++) ov[r] = xv[r] + bc + v[r];
    *(f32x4*)&out[base] = ov;
  }
}

extern "C" void kernel_launch(void* const* d_in, const int* in_sizes, int n_in,
                              void* d_out, int out_size, void* d_ws, size_t ws_size,
                              hipStream_t stream) {
  (void)in_sizes; (void)n_in; (void)out_size; (void)ws_size;
  const float* x  = (const float*)d_in[0];
  const float* wq = (const float*)d_in[1];
  const float* bq = (const float*)d_in[2];
  const float* wk = (const float*)d_in[3];
  const float* bk = (const float*)d_in[4];
  const float* wv = (const float*)d_in[5];
  const float* bv = (const float*)d_in[6];
  const float* wo = (const float*)d_in[7];
  const float* bo = (const float*)d_in[8];
  float* out = (float*)d_out;
  char* ws = (char*)d_ws;
  // workspace layout (16B aligned), ~39 MB total
  float* mean = (float*)ws;                   // 256 f32
  float* rstd = (float*)(ws + 1024);          // 256 f32
  u16* wbf = (u16*)(ws + 2048);               // 16384 bf16
  u16* Qt = (u16*)(ws + 36864);               // [B][N][64] bf16  4.72MB
  u16* Kt = Qt + (size_t)BB * NN * 64;
  u16* Vt = Kt + (size_t)BB * NN * 64;
  u16* Opart = Vt + (size_t)BB * NN * 64;     // 720 * 256*64 bf16 = 23.6MB
  float* Lsum = (float*)(Opart + (size_t)BB * FTILES * NCHUNK * 256 * 64);  // 720*256 f32
  const u16* wqb = wbf;
  const u16* wkb = wbf + 4096;
  const u16* wvb = wbf + 8192;
  const u16* wob = wbf + 12288;

  prep_kernel<<<320, 256, 0, stream>>>(x, wq, wk, wv, wo, mean, rstd, wbf);
  qkv_kernel<<<BB * NTILES, 256, 0, stream>>>(x, mean, rstd, wqb, wkb, wvb, bq, bk, Qt, Kt, Vt);
  flash_kernel<<<BB * FTILES * NCHUNK, 256, 0, stream>>>(Qt, Kt, Vt, Opart, Lsum);
  out_kernel<<<BB * NTILES, 256, 0, stream>>>(x, wob, bo, Opart, Lsum, bv, out);
}